// Round 12
// baseline (1413.881 us; speedup 1.0000x reference)
//
#include <hip/hip_runtime.h>
#include <hip/hip_bf16.h>

#define BATCH 64
#define HID 512
#define EMB 256
#define VOCAB 32000
#define G4 2048   // 4*HID

typedef __attribute__((ext_vector_type(8))) short short8;
typedef __attribute__((ext_vector_type(4))) float f32x4;
typedef __attribute__((ext_vector_type(4))) unsigned short ush4;

// ---------------- zero init ----------------
__global__ __launch_bounds__(256) void zero_kernel(float* p, int n){
    int i = blockIdx.x*256 + threadIdx.x;
    if (i < n) p[i] = 0.f;
}

// ---------------- embedding gather ----------------
__global__ __launch_bounds__(256) void embed_kernel(const int* __restrict__ tok,
                                                    const float* __restrict__ emb,
                                                    float* __restrict__ out, int T){
    int i = blockIdx.x*256 + threadIdx.x;
    int n = T*BATCH*(EMB/4);
    if (i >= n) return;
    int e4 = i % (EMB/4);
    int tb = i / (EMB/4);
    int id = tok[tb];
    reinterpret_cast<float4*>(out)[(size_t)tb*(EMB/4) + e4] =
        reinterpret_cast<const float4*>(emb + (size_t)id*EMB)[e4];
}

// round-to-nearest-even fp32 -> bf16 bits
__device__ __forceinline__ unsigned short bf16_rne(float x){
    unsigned b = __float_as_uint(x);
    return (unsigned short)((b + 0x7fffu + ((b >> 16) & 1u)) >> 16);
}
__device__ __forceinline__ void split2(float x, unsigned short& h, unsigned short& l){
    h = bf16_rne(x);
    l = bf16_rne(x - __uint_as_float((unsigned)h << 16));
}

// ---------------- fp32 -> bf16 hi/lo plane split (n mult of 4) ----------------
__global__ __launch_bounds__(256) void split_kernel(const float* __restrict__ in,
                                                    unsigned short* __restrict__ hi,
                                                    unsigned short* __restrict__ lo, int n4){
    int i = blockIdx.x*256 + threadIdx.x;
    if (i >= n4) return;
    f32x4 v = reinterpret_cast<const f32x4*>(in)[i];
    ush4 h, l;
    #pragma unroll
    for (int j = 0; j < 4; j++){ unsigned short a,b; split2(v[j], a, b); h[j]=a; l[j]=b; }
    reinterpret_cast<ush4*>(hi)[i] = h;
    reinterpret_cast<ush4*>(lo)[i] = l;
}

// ---------------- MFMA split GEMM, fp32 inputs w/ in-kernel conversion (fallback) ----------------
template<int KDIM, int NDIM>
__global__ __launch_bounds__(256) void gemm_mfma_split(
    const float* __restrict__ A, const float* __restrict__ B,
    const float* __restrict__ bias, float* __restrict__ C, int M)
{
    constexpr int LS = 40;
    __shared__ unsigned short Ah[128*LS], Al[128*LS], Bh[128*LS], Bl[128*LS];
    const int n0 = blockIdx.x*128, m0 = blockIdx.y*128;
    const int tid  = threadIdx.x;
    const int lane = tid & 63, wid = tid >> 6;
    const int wm = wid >> 1, wn = wid & 1;
    const int srow = tid >> 1, sk = (tid & 1)*16;
    f32x4 acc[4][4] = {};

    for (int k0 = 0; k0 < KDIM; k0 += 32){
        __syncthreads();
        {
            int ar = m0 + srow;
            float xv[16];
            if (ar < M){
                const float4* ap = reinterpret_cast<const float4*>(A + (size_t)ar*KDIM + k0 + sk);
                #pragma unroll
                for (int q = 0; q < 4; q++){
                    float4 v = ap[q];
                    xv[q*4+0]=v.x; xv[q*4+1]=v.y; xv[q*4+2]=v.z; xv[q*4+3]=v.w;
                }
            } else {
                #pragma unroll
                for (int q = 0; q < 16; q++) xv[q] = 0.f;
            }
            #pragma unroll
            for (int q = 0; q < 16; q++){
                unsigned short h,l; split2(xv[q], h, l);
                Ah[srow*LS + sk + q] = h;
                Al[srow*LS + sk + q] = l;
            }
        }
        {
            int br = n0 + srow;
            const float4* bp = reinterpret_cast<const float4*>(B + (size_t)br*KDIM + k0 + sk);
            #pragma unroll
            for (int q = 0; q < 4; q++){
                float4 v = bp[q];
                float xs[4] = {v.x, v.y, v.z, v.w};
                #pragma unroll
                for (int j = 0; j < 4; j++){
                    unsigned short h,l; split2(xs[j], h, l);
                    Bh[srow*LS + sk + q*4 + j] = h;
                    Bl[srow*LS + sk + q*4 + j] = l;
                }
            }
        }
        __syncthreads();
        const int fr = lane & 15, fk = (lane >> 4)*8;
        short8 a_h[4], a_l[4], b_h[4], b_l[4];
        #pragma unroll
        for (int mi = 0; mi < 4; mi++){
            int row = wm*64 + mi*16 + fr;
            a_h[mi] = *reinterpret_cast<const short8*>(&Ah[row*LS + fk]);
            a_l[mi] = *reinterpret_cast<const short8*>(&Al[row*LS + fk]);
        }
        #pragma unroll
        for (int nj = 0; nj < 4; nj++){
            int rowb = wn*64 + nj*16 + fr;
            b_h[nj] = *reinterpret_cast<const short8*>(&Bh[rowb*LS + fk]);
            b_l[nj] = *reinterpret_cast<const short8*>(&Bl[rowb*LS + fk]);
        }
        #pragma unroll
        for (int mi = 0; mi < 4; mi++)
            #pragma unroll
            for (int nj = 0; nj < 4; nj++){
                acc[mi][nj] = __builtin_amdgcn_mfma_f32_16x16x32_bf16(a_h[mi], b_h[nj], acc[mi][nj], 0,0,0);
                acc[mi][nj] = __builtin_amdgcn_mfma_f32_16x16x32_bf16(a_h[mi], b_l[nj], acc[mi][nj], 0,0,0);
                acc[mi][nj] = __builtin_amdgcn_mfma_f32_16x16x32_bf16(a_l[mi], b_h[nj], acc[mi][nj], 0,0,0);
            }
    }
    const int fr = lane & 15, fq = lane >> 4;
    #pragma unroll
    for (int nj = 0; nj < 4; nj++){
        int col = n0 + wn*64 + nj*16 + fr;
        float bv = bias[col];
        #pragma unroll
        for (int mi = 0; mi < 4; mi++){
            int rbase = m0 + wm*64 + mi*16 + fq*4;
            #pragma unroll
            for (int j = 0; j < 4; j++){
                int row = rbase + j;
                if (row < M)
                    __builtin_nontemporal_store(acc[mi][nj][j] + bv, &C[(size_t)row*NDIM + col]);
            }
        }
    }
}

// ---------------- MFMA GEMM from pre-split bf16 planes, XCD-swizzled 1D grid ----------------
// lid = m_tile*NTN + n_tile (n fastest). Bijective m204 remap: each XCD owns a
// CONTIGUOUS lid chunk -> same-XCD blocks share the A panel (L2-resident) and
// stream B once (L3-resident after first XCD). Fixes round-11's 8x B refetch
// from round-robin dispatch scattering panel-sharers across XCDs.
template<int KDIM, int NDIM, int NTN>
__global__ __launch_bounds__(256) void gemm_mfma_planes(
    const unsigned short* __restrict__ Ahi, const unsigned short* __restrict__ Alo,
    const unsigned short* __restrict__ Bhi, const unsigned short* __restrict__ Blo,
    const float* __restrict__ bias, float* __restrict__ C, int M)
{
    constexpr int LS = 40;
    __shared__ unsigned short Ah[128*LS], Al[128*LS], Bh[128*LS], Bl[128*LS];
    // bijective XCD swizzle (m204)
    const int total = gridDim.x;
    const int q = total >> 3, r = total & 7;
    const int xcd = blockIdx.x & 7, idx = blockIdx.x >> 3;
    const int lid = (xcd < r ? xcd*(q+1) : r*(q+1) + (xcd - r)*q) + idx;
    const int m0 = (lid / NTN)*128, n0 = (lid % NTN)*128;

    const int tid  = threadIdx.x;
    const int lane = tid & 63, wid = tid >> 6;
    const int wm = wid >> 1, wn = wid & 1;
    f32x4 acc[4][4] = {};
    const short8 zero8 = {0,0,0,0,0,0,0,0};

    for (int k0 = 0; k0 < KDIM; k0 += 32){
        __syncthreads();
        #pragma unroll
        for (int half = 0; half < 2; half++){
            int c = tid + half*256;
            int row = c >> 2, k8 = (c & 3)*8;
            size_t goffB = (size_t)(n0+row)*KDIM + k0 + k8;
            *reinterpret_cast<short8*>(&Bh[row*LS + k8]) =
                *reinterpret_cast<const short8*>(&Bhi[goffB]);
            *reinterpret_cast<short8*>(&Bl[row*LS + k8]) =
                *reinterpret_cast<const short8*>(&Blo[goffB]);
            int ar = m0 + row;
            if (ar < M){
                size_t goffA = (size_t)ar*KDIM + k0 + k8;
                *reinterpret_cast<short8*>(&Ah[row*LS + k8]) =
                    *reinterpret_cast<const short8*>(&Ahi[goffA]);
                *reinterpret_cast<short8*>(&Al[row*LS + k8]) =
                    *reinterpret_cast<const short8*>(&Alo[goffA]);
            } else {
                *reinterpret_cast<short8*>(&Ah[row*LS + k8]) = zero8;
                *reinterpret_cast<short8*>(&Al[row*LS + k8]) = zero8;
            }
        }
        __syncthreads();
        const int fr = lane & 15, fk = (lane >> 4)*8;
        short8 a_h[4], a_l[4], b_h[4], b_l[4];
        #pragma unroll
        for (int mi = 0; mi < 4; mi++){
            int row = wm*64 + mi*16 + fr;
            a_h[mi] = *reinterpret_cast<const short8*>(&Ah[row*LS + fk]);
            a_l[mi] = *reinterpret_cast<const short8*>(&Al[row*LS + fk]);
        }
        #pragma unroll
        for (int nj = 0; nj < 4; nj++){
            int rowb = wn*64 + nj*16 + fr;
            b_h[nj] = *reinterpret_cast<const short8*>(&Bh[rowb*LS + fk]);
            b_l[nj] = *reinterpret_cast<const short8*>(&Bl[rowb*LS + fk]);
        }
        #pragma unroll
        for (int mi = 0; mi < 4; mi++)
            #pragma unroll
            for (int nj = 0; nj < 4; nj++){
                acc[mi][nj] = __builtin_amdgcn_mfma_f32_16x16x32_bf16(a_h[mi], b_h[nj], acc[mi][nj], 0,0,0);
                acc[mi][nj] = __builtin_amdgcn_mfma_f32_16x16x32_bf16(a_h[mi], b_l[nj], acc[mi][nj], 0,0,0);
                acc[mi][nj] = __builtin_amdgcn_mfma_f32_16x16x32_bf16(a_l[mi], b_h[nj], acc[mi][nj], 0,0,0);
            }
    }
    const int fr = lane & 15, fq = lane >> 4;
    #pragma unroll
    for (int nj = 0; nj < 4; nj++){
        int col = n0 + wn*64 + nj*16 + fr;
        float bv = bias[col];
        #pragma unroll
        for (int mi = 0; mi < 4; mi++){
            int rbase = m0 + wm*64 + mi*16 + fq*4;
            #pragma unroll
            for (int j = 0; j < 4; j++){
                int row = rbase + j;
                if (row < M)
                    __builtin_nontemporal_store(acc[mi][nj][j] + bv, &C[(size_t)row*NDIM + col]);
            }
        }
    }
}

// ---------------- persistent LSTM layer (MFMA dot) — unchanged from round 11 ----------------
__global__ __launch_bounds__(256, 1) void lstm_layer_k(
    const float* __restrict__ Xp,    // [T*64, 2048]
    const float* __restrict__ Whh,   // [2048, 512]
    const float* __restrict__ hinit, // [64, 512]
    const float* __restrict__ cinit, // [64, 512]
    float* __restrict__ ys,          // [T*64, 512]
    float* __restrict__ cfin,        // [64, 512]
    int T,
    unsigned* __restrict__ flagbase)
{
    constexpr int WS = 520;
    __shared__ unsigned short wH[64*WS], wL[64*WS];
    __shared__ unsigned short hH[8*WS], hL[8*WS];
    __shared__ float red[2048 + 128];
    __shared__ unsigned short zbuf[8];

    const int bx  = blockIdx.x;
    const int hc  = bx & 31, bc = bx >> 5;
    const int hid0 = hc*16;
    const int tid = threadIdx.x;
    const int lane = tid & 63, kc = tid >> 6;
    unsigned* myflag = flagbase + (size_t)(bc*32 + hc)*16;

    if (tid < 8) zbuf[tid] = 0;

    #pragma unroll
    for (int it = 0; it < 32; it++){
        int fidx = tid + it*256;
        int lr   = fidx >> 7;
        int c4   = fidx & 127;
        int grow = (lr >> 4)*HID + hid0 + (lr & 15);
        f32x4 v = reinterpret_cast<const f32x4*>(Whh + (size_t)grow*HID)[c4];
        ush4 h, l;
        #pragma unroll
        for (int j = 0; j < 4; j++){ unsigned short a,b; split2(v[j], a, b); h[j]=a; l[j]=b; }
        *reinterpret_cast<ush4*>(&wH[lr*WS + c4*4]) = h;
        *reinterpret_cast<ush4*>(&wL[lr*WS + c4*4]) = l;
    }

    const int ub = tid >> 4;
    const int uh = tid & 15;
    float creg = 0.f;
    if (tid < 128) creg = cinit[(size_t)(bc*8 + ub)*HID + hid0 + uh];

    const size_t hbase = (size_t)bc*8*HID;
    const float* xprow = Xp + (size_t)(bc*8 + ub)*G4 + hid0 + uh;

    float xn0=0.f, xn1=0.f, xn2=0.f, xn3=0.f;
    if (tid < 128){
        const float* xpr = xprow;
        xn0 = xpr[0]; xn1 = xpr[512]; xn2 = xpr[1024]; xn3 = xpr[1536];
    }

    for (int t = 0; t < T; t++){
        {
            const f32x4* hsrc = reinterpret_cast<const f32x4*>(
                (t == 0) ? (hinit + hbase) : (ys + (size_t)(t-1)*BATCH*HID + hbase));
            #pragma unroll
            for (int j = 0; j < 4; j++){
                int fidx = tid + j*256;
                f32x4 v = hsrc[fidx];
                int e   = fidx*4;
                int row = e >> 9, col = e & 511;
                ush4 h, l;
                #pragma unroll
                for (int q = 0; q < 4; q++){ unsigned short a,b; split2(v[q], a, b); h[q]=a; l[q]=b; }
                *reinterpret_cast<ush4*>(&hH[row*WS + col]) = h;
                *reinterpret_cast<ush4*>(&hL[row*WS + col]) = l;
            }
        }
        __syncthreads();

        {
            f32x4 acc[4] = {};
            const int fr = lane & 15, fkq = lane >> 4;
            const bool breal = fr < 8;
            #pragma unroll
            for (int s = 0; s < 4; s++){
                int k0 = kc*128 + s*32 + fkq*8;
                short8 bh = breal ? *reinterpret_cast<const short8*>(&hH[fr*WS + k0])
                                  : *reinterpret_cast<const short8*>(zbuf);
                short8 bl = breal ? *reinterpret_cast<const short8*>(&hL[fr*WS + k0])
                                  : *reinterpret_cast<const short8*>(zbuf);
                #pragma unroll
                for (int m = 0; m < 4; m++){
                    short8 ah = *reinterpret_cast<const short8*>(&wH[(m*16+fr)*WS + k0]);
                    short8 al = *reinterpret_cast<const short8*>(&wL[(m*16+fr)*WS + k0]);
                    acc[m] = __builtin_amdgcn_mfma_f32_16x16x32_bf16(ah, bh, acc[m], 0,0,0);
                    acc[m] = __builtin_amdgcn_mfma_f32_16x16x32_bf16(ah, bl, acc[m], 0,0,0);
                    acc[m] = __builtin_amdgcn_mfma_f32_16x16x32_bf16(al, bh, acc[m], 0,0,0);
                }
            }
            const int b = lane & 15;
            if (b < 8){
                #pragma unroll
                for (int m = 0; m < 4; m++)
                    #pragma unroll
                    for (int qq = 0; qq < 4; qq++){
                        int rowp = m*16 + (lane >> 4)*4 + qq;
                        red[kc*512 + rowp*8 + b] = acc[m][qq];
                    }
            }
        }
        __syncthreads();

        if (tid < 64){
            #pragma unroll
            for (int b = 0; b < 8; b++)
                red[tid*8 + b] = red[tid*8 + b] + red[512 + tid*8 + b]
                               + red[1024 + tid*8 + b] + red[1536 + tid*8 + b];
        }
        __syncthreads();

        if (tid < 128){
            float gi = red[(0*16 + uh)*8 + ub] + xn0;
            float gf = red[(1*16 + uh)*8 + ub] + xn1;
            float gg = red[(2*16 + uh)*8 + ub] + xn2;
            float go = red[(3*16 + uh)*8 + ub] + xn3;
            float si = 1.f/(1.f + expf(-gi));
            float sf = 1.f/(1.f + expf(-gf));
            float so = 1.f/(1.f + expf(-go));
            float tg = tanhf(gg);
            float c = sf*creg + si*tg;
            creg = c;
            red[2048 + tid] = so * tanhf(c);
            if (t < T-1){
                const float* xpr = xprow + (size_t)(t+1)*BATCH*G4;
                xn0 = xpr[0]; xn1 = xpr[512]; xn2 = xpr[1024]; xn3 = xpr[1536];
            }
        }
        __syncthreads();

        if (tid < 64){
            if (tid < 32){
                f32x4 v = *reinterpret_cast<const f32x4*>(&red[2048 + tid*4]);
                const f32x4* addr = reinterpret_cast<const f32x4*>(
                    ys + (size_t)t*BATCH*HID
                       + (size_t)(bc*8 + (tid >> 2))*HID + hid0 + (tid & 3)*4);
                asm volatile("global_store_dwordx4 %0, %1, off sc0 sc1"
                             :: "v"(addr), "v"(v) : "memory");
            }
            if (t < T-1){
                asm volatile("s_waitcnt vmcnt(0)" ::: "memory");
                if (tid == 0)
                    __hip_atomic_store(myflag, (unsigned)(t+1),
                                       __ATOMIC_RELAXED, __HIP_MEMORY_SCOPE_AGENT);
                const unsigned tgt = (unsigned)(t+1);
                unsigned* fp = flagbase + (size_t)(bc*32 + (tid & 31))*16;
                unsigned spins = 0;
                bool done = false;
                while (!done && spins < (1u<<20)){
                    unsigned v = tgt;
                    if (tid < 32)
                        v = __hip_atomic_load(fp, __ATOMIC_RELAXED, __HIP_MEMORY_SCOPE_AGENT);
                    done = (bool)__all((int)(v >= tgt));
                    spins++;
                }
            }
        }
        __syncthreads();
    }

    if (tid < 128)
        cfin[(size_t)(bc*8 + ub)*HID + hid0 + uh] = creg;
}

extern "C" void kernel_launch(void* const* d_in, const int* in_sizes, int n_in,
                              void* d_out, int out_size, void* d_ws, size_t ws_size,
                              hipStream_t stream) {
    const int*   src      = (const int*)  d_in[0];
    const int*   trg      = (const int*)  d_in[1];
    const float* enc_emb  = (const float*)d_in[2];
    const float* enc_Wih0 = (const float*)d_in[3];
    const float* enc_Whh0 = (const float*)d_in[4];
    const float* enc_b0   = (const float*)d_in[5];
    const float* enc_Wih1 = (const float*)d_in[6];
    const float* enc_Whh1 = (const float*)d_in[7];
    const float* enc_b1   = (const float*)d_in[8];
    const float* dec_emb  = (const float*)d_in[9];
    const float* dec_Wih0 = (const float*)d_in[10];
    const float* dec_Whh0 = (const float*)d_in[11];
    const float* dec_b0   = (const float*)d_in[12];
    const float* dec_Wih1 = (const float*)d_in[13];
    const float* dec_Whh1 = (const float*)d_in[14];
    const float* dec_b1   = (const float*)d_in[15];
    const float* out_W    = (const float*)d_in[16];
    const float* out_b    = (const float*)d_in[17];

    // Big transient scratch in d_out (fp32, 100.35M elems); all dead before final GEMM.
    float* ob = (float*)d_out;
    float* Xp   = ob;                         // [3200,2048]
    float* xe   = ob + (size_t)6553600;       // [3200,256]
    float* xd   = ob + (size_t)7372800;       // [3136,256]
    float* eys0 = ob + (size_t)8175616;       // [50*64,512]
    float* eys1 = ob + (size_t)9814016;       // [50*64,512]
    float* dys0 = ob + (size_t)11452416;      // [49*64,512]

    // d_ws layout (floats then shorts).
    float* ws = (float*)d_ws;
    float* dys1 = ws;                              // [49*64,512] = 1,605,632
    float* c0   = ws + (size_t)1605632;
    float* c1   = ws + (size_t)1638400;
    float* hz   = ws + (size_t)1671168;
    unsigned* flags = (unsigned*)(ws + (size_t)1703936); // 16384 uints
    unsigned short* Whi = (unsigned short*)(ws + (size_t)1720320);
    unsigned short* Wlo = Whi + (size_t)16384000;  // 32000*512
    unsigned short* Ahi = Wlo + (size_t)16384000;
    unsigned short* Alo = Ahi + (size_t)1605632;   // 3136*512
    // Xp-GEMM plane region (appended)
    unsigned short* eW0h = Alo  + (size_t)1605632;
    unsigned short* eW0l = eW0h + (size_t)524288;   // 2048*256
    unsigned short* eW1h = eW0l + (size_t)524288;
    unsigned short* eW1l = eW1h + (size_t)1048576;  // 2048*512
    unsigned short* dW0h = eW1l + (size_t)1048576;
    unsigned short* dW0l = dW0h + (size_t)524288;
    unsigned short* dW1h = dW0l + (size_t)524288;
    unsigned short* dW1l = dW1h + (size_t)1048576;
    unsigned short* XAh  = dW1l + (size_t)1048576;
    unsigned short* XAl  = XAh  + (size_t)1638400;  // 3200*512 max
    const size_t end_final = (size_t)1720320*4 + ((size_t)16384000 + 1605632)*2*2;
    const size_t end_xp    = end_final + ((size_t)6291456 + 3276800)*2;
    const bool planes_ok = (ws_size >= end_final);
    const bool xp_ok     = (ws_size >= end_xp);

    // zero c0,c1,hz + flags
    {
        int n = 3*BATCH*HID + 4*4096;
        zero_kernel<<<(n+255)/256, 256, 0, stream>>>(c0, n);
    }

    if (planes_ok)
        split_kernel<<<(16384000/4 + 255)/256, 256, 0, stream>>>(out_W, Whi, Wlo, 16384000/4);
    if (xp_ok){
        split_kernel<<<(524288/4 + 255)/256, 256, 0, stream>>>(enc_Wih0, eW0h, eW0l, 524288/4);
        split_kernel<<<(1048576/4 + 255)/256, 256, 0, stream>>>(enc_Wih1, eW1h, eW1l, 1048576/4);
        split_kernel<<<(524288/4 + 255)/256, 256, 0, stream>>>(dec_Wih0, dW0h, dW0l, 524288/4);
        split_kernel<<<(1048576/4 + 255)/256, 256, 0, stream>>>(dec_Wih1, dW1h, dW1l, 1048576/4);
    }

    // embeddings
    embed_kernel<<<(50*BATCH*(EMB/4)+255)/256, 256, 0, stream>>>(src, enc_emb, xe, 50);
    embed_kernel<<<(49*BATCH*(EMB/4)+255)/256, 256, 0, stream>>>(trg, dec_emb, xd, 49);

    dim3 xgrid(G4/128, 25);   // fallback grid

    // ---- encoder layer 0 ----
    if (xp_ok){
        split_kernel<<<(819200/4 + 255)/256, 256, 0, stream>>>(xe, XAh, XAl, 819200/4);
        gemm_mfma_planes<EMB, G4, 16><<<400, 256, 0, stream>>>(XAh, XAl, eW0h, eW0l, enc_b0, Xp, 3200);
    } else
        gemm_mfma_split<EMB, G4><<<xgrid, 256, 0, stream>>>(xe, enc_Wih0, enc_b0, Xp, 3200);
    lstm_layer_k<<<256, 256, 0, stream>>>(Xp, enc_Whh0, hz, hz, eys0, c0, 50, flags + 0);

    // ---- encoder layer 1 ----
    if (xp_ok){
        split_kernel<<<(1638400/4 + 255)/256, 256, 0, stream>>>(eys0, XAh, XAl, 1638400/4);
        gemm_mfma_planes<HID, G4, 16><<<400, 256, 0, stream>>>(XAh, XAl, eW1h, eW1l, enc_b1, Xp, 3200);
    } else
        gemm_mfma_split<HID, G4><<<xgrid, 256, 0, stream>>>(eys0, enc_Wih1, enc_b1, Xp, 3200);
    lstm_layer_k<<<256, 256, 0, stream>>>(Xp, enc_Whh1, hz, hz, eys1, c1, 50, flags + 4096);

    // ---- decoder layer 0 ----
    if (xp_ok){
        split_kernel<<<(802816/4 + 255)/256, 256, 0, stream>>>(xd, XAh, XAl, 802816/4);
        gemm_mfma_planes<EMB, G4, 16><<<400, 256, 0, stream>>>(XAh, XAl, dW0h, dW0l, dec_b0, Xp, 3136);
    } else
        gemm_mfma_split<EMB, G4><<<xgrid, 256, 0, stream>>>(xd, dec_Wih0, dec_b0, Xp, 3136);
    lstm_layer_k<<<256, 256, 0, stream>>>(Xp, dec_Whh0, eys0 + (size_t)49*BATCH*HID, c0,
                                          dys0, c0, 49, flags + 8192);

    // ---- decoder layer 1 ----
    if (xp_ok){
        split_kernel<<<(1605632/4 + 255)/256, 256, 0, stream>>>(dys0, XAh, XAl, 1605632/4);
        gemm_mfma_planes<HID, G4, 16><<<400, 256, 0, stream>>>(XAh, XAl, dW1h, dW1l, dec_b1, Xp, 3136);
    } else
        gemm_mfma_split<HID, G4><<<xgrid, 256, 0, stream>>>(dys0, dec_Wih1, dec_b1, Xp, 3136);
    lstm_layer_k<<<256, 256, 0, stream>>>(Xp, dec_Whh1, eys1 + (size_t)49*BATCH*HID, c1,
                                          dys1, c1, 49, flags + 12288);

    // ---- final projection -> fp32 d_out [3136, 32000] ----
    if (planes_ok){
        split_kernel<<<(1605632/4 + 255)/256, 256, 0, stream>>>(dys1, Ahi, Alo, 1605632/4);
        gemm_mfma_planes<HID, VOCAB, 250><<<6250, 256, 0, stream>>>(
            Ahi, Alo, Whi, Wlo, out_b, (float*)d_out, 3136);
    } else {
        gemm_mfma_split<HID, VOCAB><<<dim3(VOCAB/128, 25), 256, 0, stream>>>(
            dys1, out_W, out_b, (float*)d_out, 3136);
    }
}

// Round 13
// 1330.649 us; speedup vs baseline: 1.0625x; 1.0625x over previous
//
#include <hip/hip_runtime.h>
#include <hip/hip_bf16.h>

#define BATCH 64
#define HID 512
#define EMB 256
#define VOCAB 32000
#define G4 2048   // 4*HID

typedef __attribute__((ext_vector_type(8))) short short8;
typedef __attribute__((ext_vector_type(4))) float f32x4;
typedef __attribute__((ext_vector_type(4))) unsigned short ush4;

// ---------------- zero init ----------------
__global__ __launch_bounds__(256) void zero_kernel(float* p, int n){
    int i = blockIdx.x*256 + threadIdx.x;
    if (i < n) p[i] = 0.f;
}

// ---------------- embedding gather ----------------
__global__ __launch_bounds__(256) void embed_kernel(const int* __restrict__ tok,
                                                    const float* __restrict__ emb,
                                                    float* __restrict__ out, int T){
    int i = blockIdx.x*256 + threadIdx.x;
    int n = T*BATCH*(EMB/4);
    if (i >= n) return;
    int e4 = i % (EMB/4);
    int tb = i / (EMB/4);
    int id = tok[tb];
    reinterpret_cast<float4*>(out)[(size_t)tb*(EMB/4) + e4] =
        reinterpret_cast<const float4*>(emb + (size_t)id*EMB)[e4];
}

// round-to-nearest-even fp32 -> bf16 bits
__device__ __forceinline__ unsigned short bf16_rne(float x){
    unsigned b = __float_as_uint(x);
    return (unsigned short)((b + 0x7fffu + ((b >> 16) & 1u)) >> 16);
}
__device__ __forceinline__ void split2(float x, unsigned short& h, unsigned short& l){
    h = bf16_rne(x);
    l = bf16_rne(x - __uint_as_float((unsigned)h << 16));
}

// ---------------- fp32 -> bf16 hi/lo plane split ----------------
__global__ __launch_bounds__(256) void split_kernel(const float* __restrict__ in,
                                                    unsigned short* __restrict__ hi,
                                                    unsigned short* __restrict__ lo, int n4){
    int i = blockIdx.x*256 + threadIdx.x;
    if (i >= n4) return;
    f32x4 v = reinterpret_cast<const f32x4*>(in)[i];
    ush4 h, l;
    #pragma unroll
    for (int j = 0; j < 4; j++){ unsigned short a,b; split2(v[j], a, b); h[j]=a; l[j]=b; }
    reinterpret_cast<ush4*>(hi)[i] = h;
    reinterpret_cast<ush4*>(lo)[i] = l;
}

// ---------------- MFMA split GEMM, fp32 inputs (fallback only) ----------------
template<int KDIM, int NDIM>
__global__ __launch_bounds__(256) void gemm_mfma_split(
    const float* __restrict__ A, const float* __restrict__ B,
    const float* __restrict__ bias, float* __restrict__ C, int M)
{
    constexpr int LS = 40;
    __shared__ unsigned short Ah[128*LS], Al[128*LS], Bh[128*LS], Bl[128*LS];
    const int n0 = blockIdx.x*128, m0 = blockIdx.y*128;
    const int tid  = threadIdx.x;
    const int lane = tid & 63, wid = tid >> 6;
    const int wm = wid >> 1, wn = wid & 1;
    const int srow = tid >> 1, sk = (tid & 1)*16;
    f32x4 acc[4][4] = {};

    for (int k0 = 0; k0 < KDIM; k0 += 32){
        __syncthreads();
        {
            int ar = m0 + srow;
            float xv[16];
            if (ar < M){
                const float4* ap = reinterpret_cast<const float4*>(A + (size_t)ar*KDIM + k0 + sk);
                #pragma unroll
                for (int q = 0; q < 4; q++){
                    float4 v = ap[q];
                    xv[q*4+0]=v.x; xv[q*4+1]=v.y; xv[q*4+2]=v.z; xv[q*4+3]=v.w;
                }
            } else {
                #pragma unroll
                for (int q = 0; q < 16; q++) xv[q] = 0.f;
            }
            #pragma unroll
            for (int q = 0; q < 16; q++){
                unsigned short h,l; split2(xv[q], h, l);
                Ah[srow*LS + sk + q] = h;
                Al[srow*LS + sk + q] = l;
            }
        }
        {
            int br = n0 + srow;
            const float4* bp = reinterpret_cast<const float4*>(B + (size_t)br*KDIM + k0 + sk);
            #pragma unroll
            for (int q = 0; q < 4; q++){
                float4 v = bp[q];
                float xs[4] = {v.x, v.y, v.z, v.w};
                #pragma unroll
                for (int j = 0; j < 4; j++){
                    unsigned short h,l; split2(xs[j], h, l);
                    Bh[srow*LS + sk + q*4 + j] = h;
                    Bl[srow*LS + sk + q*4 + j] = l;
                }
            }
        }
        __syncthreads();
        const int fr = lane & 15, fk = (lane >> 4)*8;
        short8 a_h[4], a_l[4], b_h[4], b_l[4];
        #pragma unroll
        for (int mi = 0; mi < 4; mi++){
            int row = wm*64 + mi*16 + fr;
            a_h[mi] = *reinterpret_cast<const short8*>(&Ah[row*LS + fk]);
            a_l[mi] = *reinterpret_cast<const short8*>(&Al[row*LS + fk]);
        }
        #pragma unroll
        for (int nj = 0; nj < 4; nj++){
            int rowb = wn*64 + nj*16 + fr;
            b_h[nj] = *reinterpret_cast<const short8*>(&Bh[rowb*LS + fk]);
            b_l[nj] = *reinterpret_cast<const short8*>(&Bl[rowb*LS + fk]);
        }
        #pragma unroll
        for (int mi = 0; mi < 4; mi++)
            #pragma unroll
            for (int nj = 0; nj < 4; nj++){
                acc[mi][nj] = __builtin_amdgcn_mfma_f32_16x16x32_bf16(a_h[mi], b_h[nj], acc[mi][nj], 0,0,0);
                acc[mi][nj] = __builtin_amdgcn_mfma_f32_16x16x32_bf16(a_h[mi], b_l[nj], acc[mi][nj], 0,0,0);
                acc[mi][nj] = __builtin_amdgcn_mfma_f32_16x16x32_bf16(a_l[mi], b_h[nj], acc[mi][nj], 0,0,0);
            }
    }
    const int fr = lane & 15, fq = lane >> 4;
    #pragma unroll
    for (int nj = 0; nj < 4; nj++){
        int col = n0 + wn*64 + nj*16 + fr;
        float bv = bias[col];
        #pragma unroll
        for (int mi = 0; mi < 4; mi++){
            int rbase = m0 + wm*64 + mi*16 + fq*4;
            #pragma unroll
            for (int j = 0; j < 4; j++){
                int row = rbase + j;
                if (row < M)
                    __builtin_nontemporal_store(acc[mi][nj][j] + bv, &C[(size_t)row*NDIM + col]);
            }
        }
    }
}

// ---- global_load_lds width-16 helper (size must be a literal) ----
__device__ __forceinline__ void gll16(const unsigned short* g, unsigned short* l){
    __builtin_amdgcn_global_load_lds(
        (const __attribute__((address_space(1))) unsigned int*)g,
        (__attribute__((address_space(3))) unsigned int*)l, 16, 0, 0);
}

// ---------------- plane GEMM, m97 structure: global_load_lds + XOR swizzle ----------------
// 4 linear LDS planes [128][32] bf16 (8KB each, no padding). Wave w stages plane w
// via 8x global_load_lds_dwordx4 (lane l -> lds base + l*16, HW-linear).
// Swizzle (rule #21, both sides): element belonging at linear slot (row, ce) is
// global column ce ^ (8*((row>>1)&3)); ds_read applies the same XOR. 64-lane
// ds_read_b128 then covers all 8 bank-positions exactly 2x -> conflict-free.
// XCD-bijective 1D grid (lid = m_tile*NTN + n_tile).
template<int KDIM, int NDIM, int NTN>
__global__ __launch_bounds__(256) void gemm_planes_gll(
    const unsigned short* __restrict__ Ahi, const unsigned short* __restrict__ Alo,
    const unsigned short* __restrict__ Bhi, const unsigned short* __restrict__ Blo,
    const float* __restrict__ bias, float* __restrict__ C, int M)
{
    __shared__ unsigned short P[4][128*32];   // Ah, Al, Bh, Bl
    const int total = gridDim.x;
    const int q = total >> 3, r8 = total & 7;
    const int xcd = blockIdx.x & 7, idx = blockIdx.x >> 3;
    const int lid = (xcd < r8 ? xcd*(q+1) : r8*(q+1) + (xcd - r8)*q) + idx;
    const int m0 = (lid / NTN)*128, n0 = (lid % NTN)*128;

    const int tid  = threadIdx.x;
    const int lane = tid & 63, wid = tid >> 6;
    const int wm = wid >> 1, wn = wid & 1;

    // staging: wave wid owns plane wid
    const unsigned short* gsrc = (wid == 0) ? Ahi : (wid == 1) ? Alo
                               : (wid == 2) ? Bhi : Blo;
    const int row0 = (wid < 2) ? m0 : n0;
    // lane's pre-swizzled global base: row = row0 + (lane>>2), col = 8*((lane&3)^((lane>>3)&3))
    const unsigned short* gbase = gsrc + (size_t)(row0 + (lane >> 2))*KDIM
                                       + 8*((lane & 3) ^ ((lane >> 3) & 3));
    unsigned short* lbase = &P[wid][0];

    f32x4 acc[4][4] = {};

    for (int k0 = 0; k0 < KDIM; k0 += 32){
        __syncthreads();                       // prior readers done with P
        #pragma unroll
        for (int i = 0; i < 8; i++)            // 8 chunks x 1KB = full plane
            gll16(gbase + k0 + (size_t)i*16*KDIM, lbase + i*512);
        __syncthreads();                       // compiler drains vmcnt before barrier

        const int fr = lane & 15, fkq = lane >> 4;
        const int swz = 8*(fkq ^ ((fr >> 1) & 3));   // per-lane constant
        short8 a_h[4], a_l[4], b_h[4], b_l[4];
        #pragma unroll
        for (int mi = 0; mi < 4; mi++){
            int row = wm*64 + mi*16 + fr;
            a_h[mi] = *reinterpret_cast<const short8*>(&P[0][row*32 + swz]);
            a_l[mi] = *reinterpret_cast<const short8*>(&P[1][row*32 + swz]);
        }
        #pragma unroll
        for (int nj = 0; nj < 4; nj++){
            int row = wn*64 + nj*16 + fr;
            b_h[nj] = *reinterpret_cast<const short8*>(&P[2][row*32 + swz]);
            b_l[nj] = *reinterpret_cast<const short8*>(&P[3][row*32 + swz]);
        }
        #pragma unroll
        for (int mi = 0; mi < 4; mi++)
            #pragma unroll
            for (int nj = 0; nj < 4; nj++){
                acc[mi][nj] = __builtin_amdgcn_mfma_f32_16x16x32_bf16(a_h[mi], b_h[nj], acc[mi][nj], 0,0,0);
                acc[mi][nj] = __builtin_amdgcn_mfma_f32_16x16x32_bf16(a_h[mi], b_l[nj], acc[mi][nj], 0,0,0);
                acc[mi][nj] = __builtin_amdgcn_mfma_f32_16x16x32_bf16(a_l[mi], b_h[nj], acc[mi][nj], 0,0,0);
            }
    }
    const int fr = lane & 15, fq = lane >> 4;
    #pragma unroll
    for (int nj = 0; nj < 4; nj++){
        int col = n0 + wn*64 + nj*16 + fr;
        float bv = bias[col];
        #pragma unroll
        for (int mi = 0; mi < 4; mi++){
            int rbase = m0 + wm*64 + mi*16 + fq*4;
            #pragma unroll
            for (int j = 0; j < 4; j++){
                int row = rbase + j;
                if (row < M)
                    __builtin_nontemporal_store(acc[mi][nj][j] + bv, &C[(size_t)row*NDIM + col]);
            }
        }
    }
}

// ---------------- persistent LSTM layer (MFMA dot) — unchanged from round 11 ----------------
__global__ __launch_bounds__(256, 1) void lstm_layer_k(
    const float* __restrict__ Xp,
    const float* __restrict__ Whh,
    const float* __restrict__ hinit,
    const float* __restrict__ cinit,
    float* __restrict__ ys,
    float* __restrict__ cfin,
    int T,
    unsigned* __restrict__ flagbase)
{
    constexpr int WS = 520;
    __shared__ unsigned short wH[64*WS], wL[64*WS];
    __shared__ unsigned short hH[8*WS], hL[8*WS];
    __shared__ float red[2048 + 128];
    __shared__ unsigned short zbuf[8];

    const int bx  = blockIdx.x;
    const int hc  = bx & 31, bc = bx >> 5;
    const int hid0 = hc*16;
    const int tid = threadIdx.x;
    const int lane = tid & 63, kc = tid >> 6;
    unsigned* myflag = flagbase + (size_t)(bc*32 + hc)*16;

    if (tid < 8) zbuf[tid] = 0;

    #pragma unroll
    for (int it = 0; it < 32; it++){
        int fidx = tid + it*256;
        int lr   = fidx >> 7;
        int c4   = fidx & 127;
        int grow = (lr >> 4)*HID + hid0 + (lr & 15);
        f32x4 v = reinterpret_cast<const f32x4*>(Whh + (size_t)grow*HID)[c4];
        ush4 h, l;
        #pragma unroll
        for (int j = 0; j < 4; j++){ unsigned short a,b; split2(v[j], a, b); h[j]=a; l[j]=b; }
        *reinterpret_cast<ush4*>(&wH[lr*WS + c4*4]) = h;
        *reinterpret_cast<ush4*>(&wL[lr*WS + c4*4]) = l;
    }

    const int ub = tid >> 4;
    const int uh = tid & 15;
    float creg = 0.f;
    if (tid < 128) creg = cinit[(size_t)(bc*8 + ub)*HID + hid0 + uh];

    const size_t hbase = (size_t)bc*8*HID;
    const float* xprow = Xp + (size_t)(bc*8 + ub)*G4 + hid0 + uh;

    float xn0=0.f, xn1=0.f, xn2=0.f, xn3=0.f;
    if (tid < 128){
        const float* xpr = xprow;
        xn0 = xpr[0]; xn1 = xpr[512]; xn2 = xpr[1024]; xn3 = xpr[1536];
    }

    for (int t = 0; t < T; t++){
        {
            const f32x4* hsrc = reinterpret_cast<const f32x4*>(
                (t == 0) ? (hinit + hbase) : (ys + (size_t)(t-1)*BATCH*HID + hbase));
            #pragma unroll
            for (int j = 0; j < 4; j++){
                int fidx = tid + j*256;
                f32x4 v = hsrc[fidx];
                int e   = fidx*4;
                int row = e >> 9, col = e & 511;
                ush4 h, l;
                #pragma unroll
                for (int q = 0; q < 4; q++){ unsigned short a,b; split2(v[q], a, b); h[q]=a; l[q]=b; }
                *reinterpret_cast<ush4*>(&hH[row*WS + col]) = h;
                *reinterpret_cast<ush4*>(&hL[row*WS + col]) = l;
            }
        }
        __syncthreads();

        {
            f32x4 acc[4] = {};
            const int fr = lane & 15, fkq = lane >> 4;
            const bool breal = fr < 8;
            #pragma unroll
            for (int s = 0; s < 4; s++){
                int k0 = kc*128 + s*32 + fkq*8;
                short8 bh = breal ? *reinterpret_cast<const short8*>(&hH[fr*WS + k0])
                                  : *reinterpret_cast<const short8*>(zbuf);
                short8 bl = breal ? *reinterpret_cast<const short8*>(&hL[fr*WS + k0])
                                  : *reinterpret_cast<const short8*>(zbuf);
                #pragma unroll
                for (int m = 0; m < 4; m++){
                    short8 ah = *reinterpret_cast<const short8*>(&wH[(m*16+fr)*WS + k0]);
                    short8 al = *reinterpret_cast<const short8*>(&wL[(m*16+fr)*WS + k0]);
                    acc[m] = __builtin_amdgcn_mfma_f32_16x16x32_bf16(ah, bh, acc[m], 0,0,0);
                    acc[m] = __builtin_amdgcn_mfma_f32_16x16x32_bf16(ah, bl, acc[m], 0,0,0);
                    acc[m] = __builtin_amdgcn_mfma_f32_16x16x32_bf16(al, bh, acc[m], 0,0,0);
                }
            }
            const int b = lane & 15;
            if (b < 8){
                #pragma unroll
                for (int m = 0; m < 4; m++)
                    #pragma unroll
                    for (int qq = 0; qq < 4; qq++){
                        int rowp = m*16 + (lane >> 4)*4 + qq;
                        red[kc*512 + rowp*8 + b] = acc[m][qq];
                    }
            }
        }
        __syncthreads();

        if (tid < 64){
            #pragma unroll
            for (int b = 0; b < 8; b++)
                red[tid*8 + b] = red[tid*8 + b] + red[512 + tid*8 + b]
                               + red[1024 + tid*8 + b] + red[1536 + tid*8 + b];
        }
        __syncthreads();

        if (tid < 128){
            float gi = red[(0*16 + uh)*8 + ub] + xn0;
            float gf = red[(1*16 + uh)*8 + ub] + xn1;
            float gg = red[(2*16 + uh)*8 + ub] + xn2;
            float go = red[(3*16 + uh)*8 + ub] + xn3;
            float si = 1.f/(1.f + expf(-gi));
            float sf = 1.f/(1.f + expf(-gf));
            float so = 1.f/(1.f + expf(-go));
            float tg = tanhf(gg);
            float c = sf*creg + si*tg;
            creg = c;
            red[2048 + tid] = so * tanhf(c);
            if (t < T-1){
                const float* xpr = xprow + (size_t)(t+1)*BATCH*G4;
                xn0 = xpr[0]; xn1 = xpr[512]; xn2 = xpr[1024]; xn3 = xpr[1536];
            }
        }
        __syncthreads();

        if (tid < 64){
            if (tid < 32){
                f32x4 v = *reinterpret_cast<const f32x4*>(&red[2048 + tid*4]);
                const f32x4* addr = reinterpret_cast<const f32x4*>(
                    ys + (size_t)t*BATCH*HID
                       + (size_t)(bc*8 + (tid >> 2))*HID + hid0 + (tid & 3)*4);
                asm volatile("global_store_dwordx4 %0, %1, off sc0 sc1"
                             :: "v"(addr), "v"(v) : "memory");
            }
            if (t < T-1){
                asm volatile("s_waitcnt vmcnt(0)" ::: "memory");
                if (tid == 0)
                    __hip_atomic_store(myflag, (unsigned)(t+1),
                                       __ATOMIC_RELAXED, __HIP_MEMORY_SCOPE_AGENT);
                const unsigned tgt = (unsigned)(t+1);
                unsigned* fp = flagbase + (size_t)(bc*32 + (tid & 31))*16;
                unsigned spins = 0;
                bool done = false;
                while (!done && spins < (1u<<20)){
                    unsigned v = tgt;
                    if (tid < 32)
                        v = __hip_atomic_load(fp, __ATOMIC_RELAXED, __HIP_MEMORY_SCOPE_AGENT);
                    done = (bool)__all((int)(v >= tgt));
                    spins++;
                }
            }
        }
        __syncthreads();
    }

    if (tid < 128)
        cfin[(size_t)(bc*8 + ub)*HID + hid0 + uh] = creg;
}

extern "C" void kernel_launch(void* const* d_in, const int* in_sizes, int n_in,
                              void* d_out, int out_size, void* d_ws, size_t ws_size,
                              hipStream_t stream) {
    const int*   src      = (const int*)  d_in[0];
    const int*   trg      = (const int*)  d_in[1];
    const float* enc_emb  = (const float*)d_in[2];
    const float* enc_Wih0 = (const float*)d_in[3];
    const float* enc_Whh0 = (const float*)d_in[4];
    const float* enc_b0   = (const float*)d_in[5];
    const float* enc_Wih1 = (const float*)d_in[6];
    const float* enc_Whh1 = (const float*)d_in[7];
    const float* enc_b1   = (const float*)d_in[8];
    const float* dec_emb  = (const float*)d_in[9];
    const float* dec_Wih0 = (const float*)d_in[10];
    const float* dec_Whh0 = (const float*)d_in[11];
    const float* dec_b0   = (const float*)d_in[12];
    const float* dec_Wih1 = (const float*)d_in[13];
    const float* dec_Whh1 = (const float*)d_in[14];
    const float* dec_b1   = (const float*)d_in[15];
    const float* out_W    = (const float*)d_in[16];
    const float* out_b    = (const float*)d_in[17];

    // Big transient scratch in d_out (fp32, 100.35M elems); all dead before final GEMM.
    float* ob = (float*)d_out;
    float* Xp   = ob;                         // [3200,2048]
    float* xe   = ob + (size_t)6553600;       // [3200,256]
    float* xd   = ob + (size_t)7372800;       // [3136,256]
    float* eys0 = ob + (size_t)8175616;       // [50*64,512]
    float* eys1 = ob + (size_t)9814016;       // [50*64,512]
    float* dys0 = ob + (size_t)11452416;      // [49*64,512]

    // d_ws layout. A-plane buffers sized 3200 rows so M-edge tile reads stay in-bounds.
    float* ws = (float*)d_ws;
    float* dys1 = ws;                              // [49*64,512] = 1,605,632
    float* c0   = ws + (size_t)1605632;
    float* c1   = ws + (size_t)1638400;
    float* hz   = ws + (size_t)1671168;
    unsigned* flags = (unsigned*)(ws + (size_t)1703936); // 16384 uints
    unsigned short* Whi = (unsigned short*)(ws + (size_t)1720320);
    unsigned short* Wlo = Whi + (size_t)16384000;  // 32000*512
    unsigned short* Ahi = Wlo + (size_t)16384000;
    unsigned short* Alo = Ahi + (size_t)1638400;   // 3200*512 (padded rows)
    unsigned short* eW0h = Alo  + (size_t)1638400;
    unsigned short* eW0l = eW0h + (size_t)524288;   // 2048*256
    unsigned short* eW1h = eW0l + (size_t)524288;
    unsigned short* eW1l = eW1h + (size_t)1048576;  // 2048*512
    unsigned short* dW0h = eW1l + (size_t)1048576;
    unsigned short* dW0l = dW0h + (size_t)524288;
    unsigned short* dW1h = dW0l + (size_t)524288;
    unsigned short* dW1l = dW1h + (size_t)1048576;
    unsigned short* XAh  = dW1l + (size_t)1048576;
    unsigned short* XAl  = XAh  + (size_t)1638400;  // 3200*512 max
    const size_t end_final = (size_t)1720320*4 + ((size_t)16384000 + 1638400)*2*2;
    const size_t end_xp    = end_final + ((size_t)6291456 + 3276800)*2;
    const bool planes_ok = (ws_size >= end_final);
    const bool xp_ok     = (ws_size >= end_xp);

    // zero c0,c1,hz + flags
    {
        int n = 3*BATCH*HID + 4*4096;
        zero_kernel<<<(n+255)/256, 256, 0, stream>>>(c0, n);
    }

    if (planes_ok)
        split_kernel<<<(16384000/4 + 255)/256, 256, 0, stream>>>(out_W, Whi, Wlo, 16384000/4);
    if (xp_ok){
        split_kernel<<<(524288/4 + 255)/256, 256, 0, stream>>>(enc_Wih0, eW0h, eW0l, 524288/4);
        split_kernel<<<(1048576/4 + 255)/256, 256, 0, stream>>>(enc_Wih1, eW1h, eW1l, 1048576/4);
        split_kernel<<<(524288/4 + 255)/256, 256, 0, stream>>>(dec_Wih0, dW0h, dW0l, 524288/4);
        split_kernel<<<(1048576/4 + 255)/256, 256, 0, stream>>>(dec_Wih1, dW1h, dW1l, 1048576/4);
    }

    // embeddings
    embed_kernel<<<(50*BATCH*(EMB/4)+255)/256, 256, 0, stream>>>(src, enc_emb, xe, 50);
    embed_kernel<<<(49*BATCH*(EMB/4)+255)/256, 256, 0, stream>>>(trg, dec_emb, xd, 49);

    dim3 xgrid(G4/128, 25);   // fallback grid

    // ---- encoder layer 0 ----
    if (xp_ok){
        split_kernel<<<(819200/4 + 255)/256, 256, 0, stream>>>(xe, XAh, XAl, 819200/4);
        gemm_planes_gll<EMB, G4, 16><<<400, 256, 0, stream>>>(XAh, XAl, eW0h, eW0l, enc_b0, Xp, 3200);
    } else
        gemm_mfma_split<EMB, G4><<<xgrid, 256, 0, stream>>>(xe, enc_Wih0, enc_b0, Xp, 3200);
    lstm_layer_k<<<256, 256, 0, stream>>>(Xp, enc_Whh0, hz, hz, eys0, c0, 50, flags + 0);

    // ---- encoder layer 1 ----
    if (xp_ok){
        split_kernel<<<(1638400/4 + 255)/256, 256, 0, stream>>>(eys0, XAh, XAl, 1638400/4);
        gemm_planes_gll<HID, G4, 16><<<400, 256, 0, stream>>>(XAh, XAl, eW1h, eW1l, enc_b1, Xp, 3200);
    } else
        gemm_mfma_split<HID, G4><<<xgrid, 256, 0, stream>>>(eys0, enc_Wih1, enc_b1, Xp, 3200);
    lstm_layer_k<<<256, 256, 0, stream>>>(Xp, enc_Whh1, hz, hz, eys1, c1, 50, flags + 4096);

    // ---- decoder layer 0 ----
    if (xp_ok){
        split_kernel<<<(802816/4 + 255)/256, 256, 0, stream>>>(xd, XAh, XAl, 802816/4);
        gemm_planes_gll<EMB, G4, 16><<<400, 256, 0, stream>>>(XAh, XAl, dW0h, dW0l, dec_b0, Xp, 3136);
    } else
        gemm_mfma_split<EMB, G4><<<xgrid, 256, 0, stream>>>(xd, dec_Wih0, dec_b0, Xp, 3136);
    lstm_layer_k<<<256, 256, 0, stream>>>(Xp, dec_Whh0, eys0 + (size_t)49*BATCH*HID, c0,
                                          dys0, c0, 49, flags + 8192);

    // ---- decoder layer 1 ----
    if (xp_ok){
        split_kernel<<<(1605632/4 + 255)/256, 256, 0, stream>>>(dys0, XAh, XAl, 1605632/4);
        gemm_planes_gll<HID, G4, 16><<<400, 256, 0, stream>>>(XAh, XAl, dW1h, dW1l, dec_b1, Xp, 3136);
    } else
        gemm_mfma_split<HID, G4><<<xgrid, 256, 0, stream>>>(dys0, dec_Wih1, dec_b1, Xp, 3136);
    lstm_layer_k<<<256, 256, 0, stream>>>(Xp, dec_Whh1, eys1 + (size_t)49*BATCH*HID, c1,
                                          dys1, c1, 49, flags + 12288);

    // ---- final projection -> fp32 d_out [3136, 32000] ----
    if (planes_ok){
        split_kernel<<<(1605632/4 + 255)/256, 256, 0, stream>>>(dys1, Ahi, Alo, 1605632/4);
        gemm_planes_gll<HID, VOCAB, 250><<<6250, 256, 0, stream>>>(
            Ahi, Alo, Whi, Wlo, out_b, (float*)d_out, 3136);
    } else {
        gemm_mfma_split<HID, VOCAB><<<dim3(VOCAB/128, 25), 256, 0, stream>>>(
            dys1, out_W, out_b, (float*)d_out, 3136);
    }
}

// Round 14
// 1191.071 us; speedup vs baseline: 1.1871x; 1.1172x over previous
//
#include <hip/hip_runtime.h>
#include <hip/hip_bf16.h>

#define BATCH 64
#define HID 512
#define EMB 256
#define VOCAB 32000
#define G4 2048   // 4*HID

typedef __attribute__((ext_vector_type(8))) short short8;
typedef __attribute__((ext_vector_type(4))) float f32x4;
typedef __attribute__((ext_vector_type(4))) unsigned short ush4;

// ---------------- zero init ----------------
__global__ __launch_bounds__(256) void zero_kernel(float* p, int n){
    int i = blockIdx.x*256 + threadIdx.x;
    if (i < n) p[i] = 0.f;
}

// ---------------- embedding gather ----------------
__global__ __launch_bounds__(256) void embed_kernel(const int* __restrict__ tok,
                                                    const float* __restrict__ emb,
                                                    float* __restrict__ out, int T){
    int i = blockIdx.x*256 + threadIdx.x;
    int n = T*BATCH*(EMB/4);
    if (i >= n) return;
    int e4 = i % (EMB/4);
    int tb = i / (EMB/4);
    int id = tok[tb];
    reinterpret_cast<float4*>(out)[(size_t)tb*(EMB/4) + e4] =
        reinterpret_cast<const float4*>(emb + (size_t)id*EMB)[e4];
}

// round-to-nearest-even fp32 -> bf16 bits
__device__ __forceinline__ unsigned short bf16_rne(float x){
    unsigned b = __float_as_uint(x);
    return (unsigned short)((b + 0x7fffu + ((b >> 16) & 1u)) >> 16);
}
__device__ __forceinline__ void split2(float x, unsigned short& h, unsigned short& l){
    h = bf16_rne(x);
    l = bf16_rne(x - __uint_as_float((unsigned)h << 16));
}

// ---------------- fp32 -> bf16 hi/lo plane split ----------------
__global__ __launch_bounds__(256) void split_kernel(const float* __restrict__ in,
                                                    unsigned short* __restrict__ hi,
                                                    unsigned short* __restrict__ lo, int n4){
    int i = blockIdx.x*256 + threadIdx.x;
    if (i >= n4) return;
    f32x4 v = reinterpret_cast<const f32x4*>(in)[i];
    ush4 h, l;
    #pragma unroll
    for (int j = 0; j < 4; j++){ unsigned short a,b; split2(v[j], a, b); h[j]=a; l[j]=b; }
    reinterpret_cast<ush4*>(hi)[i] = h;
    reinterpret_cast<ush4*>(lo)[i] = l;
}

// ---------------- MFMA split GEMM, fp32 inputs (fallback only) ----------------
template<int KDIM, int NDIM>
__global__ __launch_bounds__(256) void gemm_mfma_split(
    const float* __restrict__ A, const float* __restrict__ B,
    const float* __restrict__ bias, float* __restrict__ C, int M)
{
    constexpr int LS = 40;
    __shared__ unsigned short Ah[128*LS], Al[128*LS], Bh[128*LS], Bl[128*LS];
    const int n0 = blockIdx.x*128, m0 = blockIdx.y*128;
    const int tid  = threadIdx.x;
    const int lane = tid & 63, wid = tid >> 6;
    const int wm = wid >> 1, wn = wid & 1;
    const int srow = tid >> 1, sk = (tid & 1)*16;
    f32x4 acc[4][4] = {};

    for (int k0 = 0; k0 < KDIM; k0 += 32){
        __syncthreads();
        {
            int ar = m0 + srow;
            float xv[16];
            if (ar < M){
                const float4* ap = reinterpret_cast<const float4*>(A + (size_t)ar*KDIM + k0 + sk);
                #pragma unroll
                for (int q = 0; q < 4; q++){
                    float4 v = ap[q];
                    xv[q*4+0]=v.x; xv[q*4+1]=v.y; xv[q*4+2]=v.z; xv[q*4+3]=v.w;
                }
            } else {
                #pragma unroll
                for (int q = 0; q < 16; q++) xv[q] = 0.f;
            }
            #pragma unroll
            for (int q = 0; q < 16; q++){
                unsigned short h,l; split2(xv[q], h, l);
                Ah[srow*LS + sk + q] = h;
                Al[srow*LS + sk + q] = l;
            }
        }
        {
            int br = n0 + srow;
            const float4* bp = reinterpret_cast<const float4*>(B + (size_t)br*KDIM + k0 + sk);
            #pragma unroll
            for (int q = 0; q < 4; q++){
                float4 v = bp[q];
                float xs[4] = {v.x, v.y, v.z, v.w};
                #pragma unroll
                for (int j = 0; j < 4; j++){
                    unsigned short h,l; split2(xs[j], h, l);
                    Bh[srow*LS + sk + q*4 + j] = h;
                    Bl[srow*LS + sk + q*4 + j] = l;
                }
            }
        }
        __syncthreads();
        const int fr = lane & 15, fk = (lane >> 4)*8;
        short8 a_h[4], a_l[4], b_h[4], b_l[4];
        #pragma unroll
        for (int mi = 0; mi < 4; mi++){
            int row = wm*64 + mi*16 + fr;
            a_h[mi] = *reinterpret_cast<const short8*>(&Ah[row*LS + fk]);
            a_l[mi] = *reinterpret_cast<const short8*>(&Al[row*LS + fk]);
        }
        #pragma unroll
        for (int nj = 0; nj < 4; nj++){
            int rowb = wn*64 + nj*16 + fr;
            b_h[nj] = *reinterpret_cast<const short8*>(&Bh[rowb*LS + fk]);
            b_l[nj] = *reinterpret_cast<const short8*>(&Bl[rowb*LS + fk]);
        }
        #pragma unroll
        for (int mi = 0; mi < 4; mi++)
            #pragma unroll
            for (int nj = 0; nj < 4; nj++){
                acc[mi][nj] = __builtin_amdgcn_mfma_f32_16x16x32_bf16(a_h[mi], b_h[nj], acc[mi][nj], 0,0,0);
                acc[mi][nj] = __builtin_amdgcn_mfma_f32_16x16x32_bf16(a_h[mi], b_l[nj], acc[mi][nj], 0,0,0);
                acc[mi][nj] = __builtin_amdgcn_mfma_f32_16x16x32_bf16(a_l[mi], b_h[nj], acc[mi][nj], 0,0,0);
            }
    }
    const int fr = lane & 15, fq = lane >> 4;
    #pragma unroll
    for (int nj = 0; nj < 4; nj++){
        int col = n0 + wn*64 + nj*16 + fr;
        float bv = bias[col];
        #pragma unroll
        for (int mi = 0; mi < 4; mi++){
            int rbase = m0 + wm*64 + mi*16 + fq*4;
            #pragma unroll
            for (int j = 0; j < 4; j++){
                int row = rbase + j;
                if (row < M)
                    __builtin_nontemporal_store(acc[mi][nj][j] + bv, &C[(size_t)row*NDIM + col]);
            }
        }
    }
}

// ---- global_load_lds width-16 helper (size must be a literal) ----
__device__ __forceinline__ void gll16(const unsigned short* g, unsigned short* l){
    __builtin_amdgcn_global_load_lds(
        (const __attribute__((address_space(1))) unsigned int*)g,
        (__attribute__((address_space(3))) unsigned int*)l, 16, 0, 0);
}

// ---------------- plane GEMM, m97 structure + m-fastest XCD chunking ----------------
// lid = n_tile*NTM + m_tile (M FASTEST). Bijective XCD chunking gives each XCD a
// contiguous n-range: every B tile is fetched by exactly ONE XCD and reused by the
// 25 temporally-adjacent m-blocks (L2-hot); A re-reads are L3-served. Fixes the
// round-13 B re-stream (FETCH 812 MB ~= 3x B from C-write L3 flushing).
template<int KDIM, int NDIM, int NTM>
__global__ __launch_bounds__(256) void gemm_planes_gll(
    const unsigned short* __restrict__ Ahi, const unsigned short* __restrict__ Alo,
    const unsigned short* __restrict__ Bhi, const unsigned short* __restrict__ Blo,
    const float* __restrict__ bias, float* __restrict__ C, int M)
{
    __shared__ unsigned short P[4][128*32];   // Ah, Al, Bh, Bl
    const int total = gridDim.x;
    const int q = total >> 3, r8 = total & 7;
    const int xcd = blockIdx.x & 7, idx = blockIdx.x >> 3;
    const int lid = (xcd < r8 ? xcd*(q+1) : r8*(q+1) + (xcd - r8)*q) + idx;
    const int m0 = (lid % NTM)*128, n0 = (lid / NTM)*128;

    const int tid  = threadIdx.x;
    const int lane = tid & 63, wid = tid >> 6;
    const int wm = wid >> 1, wn = wid & 1;

    const unsigned short* gsrc = (wid == 0) ? Ahi : (wid == 1) ? Alo
                               : (wid == 2) ? Bhi : Blo;
    const int row0 = (wid < 2) ? m0 : n0;
    const unsigned short* gbase = gsrc + (size_t)(row0 + (lane >> 2))*KDIM
                                       + 8*((lane & 3) ^ ((lane >> 3) & 3));
    unsigned short* lbase = &P[wid][0];

    f32x4 acc[4][4] = {};

    for (int k0 = 0; k0 < KDIM; k0 += 32){
        __syncthreads();
        #pragma unroll
        for (int i = 0; i < 8; i++)
            gll16(gbase + k0 + (size_t)i*16*KDIM, lbase + i*512);
        __syncthreads();

        const int fr = lane & 15, fkq = lane >> 4;
        const int swz = 8*(fkq ^ ((fr >> 1) & 3));
        short8 a_h[4], a_l[4], b_h[4], b_l[4];
        #pragma unroll
        for (int mi = 0; mi < 4; mi++){
            int row = wm*64 + mi*16 + fr;
            a_h[mi] = *reinterpret_cast<const short8*>(&P[0][row*32 + swz]);
            a_l[mi] = *reinterpret_cast<const short8*>(&P[1][row*32 + swz]);
        }
        #pragma unroll
        for (int nj = 0; nj < 4; nj++){
            int row = wn*64 + nj*16 + fr;
            b_h[nj] = *reinterpret_cast<const short8*>(&P[2][row*32 + swz]);
            b_l[nj] = *reinterpret_cast<const short8*>(&P[3][row*32 + swz]);
        }
        #pragma unroll
        for (int mi = 0; mi < 4; mi++)
            #pragma unroll
            for (int nj = 0; nj < 4; nj++){
                acc[mi][nj] = __builtin_amdgcn_mfma_f32_16x16x32_bf16(a_h[mi], b_h[nj], acc[mi][nj], 0,0,0);
                acc[mi][nj] = __builtin_amdgcn_mfma_f32_16x16x32_bf16(a_h[mi], b_l[nj], acc[mi][nj], 0,0,0);
                acc[mi][nj] = __builtin_amdgcn_mfma_f32_16x16x32_bf16(a_l[mi], b_h[nj], acc[mi][nj], 0,0,0);
            }
    }
    const int fr = lane & 15, fq = lane >> 4;
    #pragma unroll
    for (int nj = 0; nj < 4; nj++){
        int col = n0 + wn*64 + nj*16 + fr;
        float bv = bias[col];
        #pragma unroll
        for (int mi = 0; mi < 4; mi++){
            int rbase = m0 + wm*64 + mi*16 + fq*4;
            #pragma unroll
            for (int j = 0; j < 4; j++){
                int row = rbase + j;
                if (row < M)
                    __builtin_nontemporal_store(acc[mi][nj][j] + bv, &C[(size_t)row*NDIM + col]);
            }
        }
    }
}

// ---------------- persistent LSTM layer body (weights in VGPR MFMA fragments) ----------------
// Block (hc=bx&31, bc=bx>>5): 16 hid x 8 batch. Each lane holds its loop-invariant
// Whh fragments ah[4][4]/al[4][4] (128 VGPRs, fully unrolled -> registers, rule #20).
// LDS: only h-stage (16.6KB) + red (8.7KB) -> ~26KB -> 2 blocks/CU possible.
// Exchange protocol unchanged (sc-store h + per-block epoch flags + parallel poll).
__device__ __forceinline__ void lstm_body(
    const float* __restrict__ Xp, const float* __restrict__ Whh,
    const float* __restrict__ hinit, const float* __restrict__ cinit,
    float* __restrict__ ys, float* __restrict__ cfin,
    int T, unsigned* __restrict__ flagbase, int bx)
{
    constexpr int WS = 520;
    __shared__ unsigned short hH[8*WS], hL[8*WS];     // 16.6 KB
    __shared__ float red[2048 + 128];                 // 8.7 KB
    __shared__ unsigned short zbuf[8];

    const int hc  = bx & 31, bc = bx >> 5;
    const int hid0 = hc*16;
    const int tid = threadIdx.x;
    const int lane = tid & 63, kc = tid >> 6;
    const int fr = lane & 15, fkq = lane >> 4;
    unsigned* myflag = flagbase + (size_t)(bc*32 + hc)*16;

    if (tid < 8) zbuf[tid] = 0;

    // ---- Whh -> per-lane register fragments (once; loop-invariant) ----
    short8 ah[4][4], al[4][4];
    #pragma unroll
    for (int m = 0; m < 4; m++){
        const float* wr = Whh + (size_t)(m*HID + hid0 + fr)*HID;
        #pragma unroll
        for (int s = 0; s < 4; s++){
            int k0 = kc*128 + s*32 + fkq*8;
            f32x4 v0 = *reinterpret_cast<const f32x4*>(wr + k0);
            f32x4 v1 = *reinterpret_cast<const f32x4*>(wr + k0 + 4);
            short8 h8, l8;
            float xv[8] = {v0[0],v0[1],v0[2],v0[3],v1[0],v1[1],v1[2],v1[3]};
            #pragma unroll
            for (int j = 0; j < 8; j++){
                unsigned short hh, ll; split2(xv[j], hh, ll);
                h8[j] = (short)hh; l8[j] = (short)ll;
            }
            ah[m][s] = h8; al[m][s] = l8;
        }
    }

    const int ub = tid >> 4;
    const int uh = tid & 15;
    float creg = 0.f;
    if (tid < 128) creg = cinit[(size_t)(bc*8 + ub)*HID + hid0 + uh];

    const size_t hbase = (size_t)bc*8*HID;
    const float* xprow = Xp + (size_t)(bc*8 + ub)*G4 + hid0 + uh;

    float xn0=0.f, xn1=0.f, xn2=0.f, xn3=0.f;
    if (tid < 128){
        const float* xpr = xprow;
        xn0 = xpr[0]; xn1 = xpr[512]; xn2 = xpr[1024]; xn3 = xpr[1536];
    }

    for (int t = 0; t < T; t++){
        // ---- stage h(t-1): cached fp32 loads -> bf16 hi/lo LDS ----
        {
            const f32x4* hsrc = reinterpret_cast<const f32x4*>(
                (t == 0) ? (hinit + hbase) : (ys + (size_t)(t-1)*BATCH*HID + hbase));
            #pragma unroll
            for (int j = 0; j < 4; j++){
                int fidx = tid + j*256;
                f32x4 v = hsrc[fidx];
                int e   = fidx*4;
                int row = e >> 9, col = e & 511;
                ush4 h, l;
                #pragma unroll
                for (int qq = 0; qq < 4; qq++){ unsigned short a,b; split2(v[qq], a, b); h[qq]=a; l[qq]=b; }
                *reinterpret_cast<ush4*>(&hH[row*WS + col]) = h;
                *reinterpret_cast<ush4*>(&hL[row*WS + col]) = l;
            }
        }
        __syncthreads();

        // ---- MFMA partial dots (weights from registers, h from LDS) ----
        {
            f32x4 acc4[4] = {};
            const bool breal = fr < 8;
            #pragma unroll
            for (int s = 0; s < 4; s++){
                int k0 = kc*128 + s*32 + fkq*8;
                short8 bh = breal ? *reinterpret_cast<const short8*>(&hH[fr*WS + k0])
                                  : *reinterpret_cast<const short8*>(zbuf);
                short8 bl = breal ? *reinterpret_cast<const short8*>(&hL[fr*WS + k0])
                                  : *reinterpret_cast<const short8*>(zbuf);
                #pragma unroll
                for (int m = 0; m < 4; m++){
                    acc4[m] = __builtin_amdgcn_mfma_f32_16x16x32_bf16(ah[m][s], bh, acc4[m], 0,0,0);
                    acc4[m] = __builtin_amdgcn_mfma_f32_16x16x32_bf16(ah[m][s], bl, acc4[m], 0,0,0);
                    acc4[m] = __builtin_amdgcn_mfma_f32_16x16x32_bf16(al[m][s], bh, acc4[m], 0,0,0);
                }
            }
            const int b = lane & 15;
            if (b < 8){
                #pragma unroll
                for (int m = 0; m < 4; m++)
                    #pragma unroll
                    for (int qq = 0; qq < 4; qq++){
                        int rowp = m*16 + (lane >> 4)*4 + qq;
                        red[kc*512 + rowp*8 + b] = acc4[m][qq];
                    }
            }
        }
        __syncthreads();

        if (tid < 64){
            #pragma unroll
            for (int b = 0; b < 8; b++)
                red[tid*8 + b] = red[tid*8 + b] + red[512 + tid*8 + b]
                               + red[1024 + tid*8 + b] + red[1536 + tid*8 + b];
        }
        __syncthreads();

        if (tid < 128){
            float gi = red[(0*16 + uh)*8 + ub] + xn0;
            float gf = red[(1*16 + uh)*8 + ub] + xn1;
            float gg = red[(2*16 + uh)*8 + ub] + xn2;
            float go = red[(3*16 + uh)*8 + ub] + xn3;
            float si = 1.f/(1.f + expf(-gi));
            float sf = 1.f/(1.f + expf(-gf));
            float so = 1.f/(1.f + expf(-go));
            float tg = tanhf(gg);
            float c = sf*creg + si*tg;
            creg = c;
            red[2048 + tid] = so * tanhf(c);
            if (t < T-1){
                const float* xpr = xprow + (size_t)(t+1)*BATCH*G4;
                xn0 = xpr[0]; xn1 = xpr[512]; xn2 = xpr[1024]; xn3 = xpr[1536];
            }
        }
        __syncthreads();

        if (tid < 64){
            if (tid < 32){
                f32x4 v = *reinterpret_cast<const f32x4*>(&red[2048 + tid*4]);
                const f32x4* addr = reinterpret_cast<const f32x4*>(
                    ys + (size_t)t*BATCH*HID
                       + (size_t)(bc*8 + (tid >> 2))*HID + hid0 + (tid & 3)*4);
                asm volatile("global_store_dwordx4 %0, %1, off sc0 sc1"
                             :: "v"(addr), "v"(v) : "memory");
            }
            if (t < T-1){
                asm volatile("s_waitcnt vmcnt(0)" ::: "memory");
                if (tid == 0)
                    __hip_atomic_store(myflag, (unsigned)(t+1),
                                       __ATOMIC_RELAXED, __HIP_MEMORY_SCOPE_AGENT);
                const unsigned tgt = (unsigned)(t+1);
                unsigned* fp = flagbase + (size_t)(bc*32 + (tid & 31))*16;
                unsigned spins = 0;
                bool done = false;
                while (!done && spins < (1u<<20)){
                    unsigned v = tgt;
                    if (tid < 32)
                        v = __hip_atomic_load(fp, __ATOMIC_RELAXED, __HIP_MEMORY_SCOPE_AGENT);
                    done = (bool)__all((int)(v >= tgt));
                    spins++;
                }
            }
        }
        __syncthreads();
    }

    if (tid < 128)
        cfin[(size_t)(bc*8 + ub)*HID + hid0 + uh] = creg;
}

__global__ __launch_bounds__(256, 2) void lstm_layer_k(
    const float* Xp, const float* Whh, const float* hinit, const float* cinit,
    float* ys, float* cfin, int T, unsigned* flagbase)
{
    lstm_body(Xp, Whh, hinit, cinit, ys, cfin, T, flagbase, blockIdx.x);
}

// Two independent layers concurrently: blocks 0-255 role 0, 256-511 role 1.
// Flag groups never span roles -> safe even if co-residency fails (serial fallback).
__global__ __launch_bounds__(256, 2) void lstm_dual_k(
    const float* Xp0, const float* Whh0, const float* hi0, const float* ci0,
    float* ys0, float* cf0, int T0, unsigned* fl0,
    const float* Xp1, const float* Whh1, const float* hi1, const float* ci1,
    float* ys1, float* cf1, int T1, unsigned* fl1)
{
    const int role = blockIdx.x >> 8;
    const int bx = blockIdx.x & 255;
    const float* Xp   = role ? Xp1 : Xp0;
    const float* Whh  = role ? Whh1 : Whh0;
    const float* hi   = role ? hi1 : hi0;
    const float* ci   = role ? ci1 : ci0;
    float* ys         = role ? ys1 : ys0;
    float* cf         = role ? cf1 : cf0;
    int T             = role ? T1 : T0;
    unsigned* fl      = role ? fl1 : fl0;
    lstm_body(Xp, Whh, hi, ci, ys, cf, T, fl, bx);
}

extern "C" void kernel_launch(void* const* d_in, const int* in_sizes, int n_in,
                              void* d_out, int out_size, void* d_ws, size_t ws_size,
                              hipStream_t stream) {
    const int*   src      = (const int*)  d_in[0];
    const int*   trg      = (const int*)  d_in[1];
    const float* enc_emb  = (const float*)d_in[2];
    const float* enc_Wih0 = (const float*)d_in[3];
    const float* enc_Whh0 = (const float*)d_in[4];
    const float* enc_b0   = (const float*)d_in[5];
    const float* enc_Wih1 = (const float*)d_in[6];
    const float* enc_Whh1 = (const float*)d_in[7];
    const float* enc_b1   = (const float*)d_in[8];
    const float* dec_emb  = (const float*)d_in[9];
    const float* dec_Wih0 = (const float*)d_in[10];
    const float* dec_Whh0 = (const float*)d_in[11];
    const float* dec_b0   = (const float*)d_in[12];
    const float* dec_Wih1 = (const float*)d_in[13];
    const float* dec_Whh1 = (const float*)d_in[14];
    const float* dec_b1   = (const float*)d_in[15];
    const float* out_W    = (const float*)d_in[16];
    const float* out_b    = (const float*)d_in[17];

    // Big transient scratch in d_out (fp32, 100.35M elems); all dead before final GEMM.
    float* ob = (float*)d_out;
    float* Xp   = ob;                         // [3200,2048]
    float* xe   = ob + (size_t)6553600;       // [3200,256]
    float* xd   = ob + (size_t)7372800;       // [3136,256]
    float* eys0 = ob + (size_t)8175616;       // [50*64,512]
    float* eys1 = ob + (size_t)9814016;       // [50*64,512]
    float* dys0 = ob + (size_t)11452416;      // [49*64,512]
    float* Xp2  = ob + (size_t)13058048;      // [3136,2048] (decL0 Xp, concurrent with Xp)

    // d_ws layout (round-13 unchanged).
    float* ws = (float*)d_ws;
    float* dys1 = ws;                              // [49*64,512]
    float* c0   = ws + (size_t)1605632;
    float* c1   = ws + (size_t)1638400;
    float* hz   = ws + (size_t)1671168;
    unsigned* flags = (unsigned*)(ws + (size_t)1703936); // 16384 uints
    unsigned short* Whi = (unsigned short*)(ws + (size_t)1720320);
    unsigned short* Wlo = Whi + (size_t)16384000;  // 32000*512
    unsigned short* Ahi = Wlo + (size_t)16384000;
    unsigned short* Alo = Ahi + (size_t)1638400;   // 3200*512 (padded rows)
    unsigned short* eW0h = Alo  + (size_t)1638400;
    unsigned short* eW0l = eW0h + (size_t)524288;
    unsigned short* eW1h = eW0l + (size_t)524288;
    unsigned short* eW1l = eW1h + (size_t)1048576;
    unsigned short* dW0h = eW1l + (size_t)1048576;
    unsigned short* dW0l = dW0h + (size_t)524288;
    unsigned short* dW1h = dW0l + (size_t)524288;
    unsigned short* dW1l = dW1h + (size_t)1048576;
    unsigned short* XAh  = dW1l + (size_t)1048576;
    unsigned short* XAl  = XAh  + (size_t)1638400;
    const size_t end_final = (size_t)1720320*4 + ((size_t)16384000 + 1638400)*2*2;
    const size_t end_xp    = end_final + ((size_t)6291456 + 3276800)*2;
    const bool planes_ok = (ws_size >= end_final);
    const bool xp_ok     = (ws_size >= end_xp);

    // zero c0,c1,hz + flags
    {
        int n = 3*BATCH*HID + 4*4096;
        zero_kernel<<<(n+255)/256, 256, 0, stream>>>(c0, n);
    }

    if (planes_ok)
        split_kernel<<<(16384000/4 + 255)/256, 256, 0, stream>>>(out_W, Whi, Wlo, 16384000/4);
    if (xp_ok){
        split_kernel<<<(524288/4 + 255)/256, 256, 0, stream>>>(enc_Wih0, eW0h, eW0l, 524288/4);
        split_kernel<<<(1048576/4 + 255)/256, 256, 0, stream>>>(enc_Wih1, eW1h, eW1l, 1048576/4);
        split_kernel<<<(524288/4 + 255)/256, 256, 0, stream>>>(dec_Wih0, dW0h, dW0l, 524288/4);
        split_kernel<<<(1048576/4 + 255)/256, 256, 0, stream>>>(dec_Wih1, dW1h, dW1l, 1048576/4);
    }

    // embeddings
    embed_kernel<<<(50*BATCH*(EMB/4)+255)/256, 256, 0, stream>>>(src, enc_emb, xe, 50);
    embed_kernel<<<(49*BATCH*(EMB/4)+255)/256, 256, 0, stream>>>(trg, dec_emb, xd, 49);

    dim3 xgrid(G4/128, 25);   // fallback grid

    // ---- encoder layer 0 ----
    if (xp_ok){
        split_kernel<<<(819200/4 + 255)/256, 256, 0, stream>>>(xe, XAh, XAl, 819200/4);
        gemm_planes_gll<EMB, G4, 25><<<400, 256, 0, stream>>>(XAh, XAl, eW0h, eW0l, enc_b0, Xp, 3200);
    } else
        gemm_mfma_split<EMB, G4><<<xgrid, 256, 0, stream>>>(xe, enc_Wih0, enc_b0, Xp, 3200);
    lstm_layer_k<<<256, 256, 0, stream>>>(Xp, enc_Whh0, hz, hz, eys0, c0, 50, flags + 0);

    // ---- Xp for encoder layer 1 (from eys0) and decoder layer 0 (from xd) ----
    if (xp_ok){
        split_kernel<<<(1638400/4 + 255)/256, 256, 0, stream>>>(eys0, XAh, XAl, 1638400/4);
        gemm_planes_gll<HID, G4, 25><<<400, 256, 0, stream>>>(XAh, XAl, eW1h, eW1l, enc_b1, Xp, 3200);
        split_kernel<<<(802816/4 + 255)/256, 256, 0, stream>>>(xd, XAh, XAl, 802816/4);
        gemm_planes_gll<EMB, G4, 25><<<400, 256, 0, stream>>>(XAh, XAl, dW0h, dW0l, dec_b0, Xp2, 3136);
    } else {
        gemm_mfma_split<HID, G4><<<xgrid, 256, 0, stream>>>(eys0, enc_Wih1, enc_b1, Xp, 3200);
        gemm_mfma_split<EMB, G4><<<xgrid, 256, 0, stream>>>(xd, dec_Wih0, dec_b0, Xp2, 3136);
    }

    // ---- encoder layer 1 AND decoder layer 0 CONCURRENTLY (independent) ----
    lstm_dual_k<<<512, 256, 0, stream>>>(
        Xp,  enc_Whh1, hz,                            hz, eys1, c1, 50, flags + 4096,
        Xp2, dec_Whh0, eys0 + (size_t)49*BATCH*HID,   c0, dys0, c0, 49, flags + 8192);

    // ---- decoder layer 1 ----
    if (xp_ok){
        split_kernel<<<(1605632/4 + 255)/256, 256, 0, stream>>>(dys0, XAh, XAl, 1605632/4);
        gemm_planes_gll<HID, G4, 25><<<400, 256, 0, stream>>>(XAh, XAl, dW1h, dW1l, dec_b1, Xp, 3136);
    } else
        gemm_mfma_split<HID, G4><<<xgrid, 256, 0, stream>>>(dys0, dec_Wih1, dec_b1, Xp, 3136);
    lstm_layer_k<<<256, 256, 0, stream>>>(Xp, dec_Whh1, eys1 + (size_t)49*BATCH*HID, c1,
                                          dys1, c1, 49, flags + 12288);

    // ---- final projection -> fp32 d_out [3136, 32000] ----
    if (planes_ok){
        split_kernel<<<(1605632/4 + 255)/256, 256, 0, stream>>>(dys1, Ahi, Alo, 1605632/4);
        gemm_planes_gll<HID, VOCAB, 25><<<6250, 256, 0, stream>>>(
            Ahi, Alo, Whi, Wlo, out_b, (float*)d_out, 3136);
    } else {
        gemm_mfma_split<HID, VOCAB><<<dim3(VOCAB/128, 25), 256, 0, stream>>>(
            dys1, out_W, out_b, (float*)d_out, 3136);
    }
}

// Round 15
// 1017.276 us; speedup vs baseline: 1.3899x; 1.1708x over previous
//
#include <hip/hip_runtime.h>
#include <hip/hip_bf16.h>

#define BATCH 64
#define HID 512
#define EMB 256
#define VOCAB 32000
#define G4 2048   // 4*HID

typedef __attribute__((ext_vector_type(8))) short short8;
typedef __attribute__((ext_vector_type(4))) float f32x4;
typedef __attribute__((ext_vector_type(4))) unsigned short ush4;

// ---------------- zero init ----------------
__global__ __launch_bounds__(256) void zero_kernel(float* p, int n){
    int i = blockIdx.x*256 + threadIdx.x;
    if (i < n) p[i] = 0.f;
}

// ---------------- embedding gather ----------------
__global__ __launch_bounds__(256) void embed_kernel(const int* __restrict__ tok,
                                                    const float* __restrict__ emb,
                                                    float* __restrict__ out, int T){
    int i = blockIdx.x*256 + threadIdx.x;
    int n = T*BATCH*(EMB/4);
    if (i >= n) return;
    int e4 = i % (EMB/4);
    int tb = i / (EMB/4);
    int id = tok[tb];
    reinterpret_cast<float4*>(out)[(size_t)tb*(EMB/4) + e4] =
        reinterpret_cast<const float4*>(emb + (size_t)id*EMB)[e4];
}

// round-to-nearest-even fp32 -> bf16 bits
__device__ __forceinline__ unsigned short bf16_rne(float x){
    unsigned b = __float_as_uint(x);
    return (unsigned short)((b + 0x7fffu + ((b >> 16) & 1u)) >> 16);
}
__device__ __forceinline__ void split2(float x, unsigned short& h, unsigned short& l){
    h = bf16_rne(x);
    l = bf16_rne(x - __uint_as_float((unsigned)h << 16));
}

// ---------------- fp32 -> bf16 hi/lo plane split ----------------
__global__ __launch_bounds__(256) void split_kernel(const float* __restrict__ in,
                                                    unsigned short* __restrict__ hi,
                                                    unsigned short* __restrict__ lo, int n4){
    int i = blockIdx.x*256 + threadIdx.x;
    if (i >= n4) return;
    f32x4 v = reinterpret_cast<const f32x4*>(in)[i];
    ush4 h, l;
    #pragma unroll
    for (int j = 0; j < 4; j++){ unsigned short a,b; split2(v[j], a, b); h[j]=a; l[j]=b; }
    reinterpret_cast<ush4*>(hi)[i] = h;
    reinterpret_cast<ush4*>(lo)[i] = l;
}

// hi-only split (for the final GEMM's B; lo plane unused there)
__global__ __launch_bounds__(256) void split_hi_kernel(const float* __restrict__ in,
                                                       unsigned short* __restrict__ hi, int n4){
    int i = blockIdx.x*256 + threadIdx.x;
    if (i >= n4) return;
    f32x4 v = reinterpret_cast<const f32x4*>(in)[i];
    ush4 h;
    #pragma unroll
    for (int j = 0; j < 4; j++) h[j] = bf16_rne(v[j]);
    reinterpret_cast<ush4*>(hi)[i] = h;
}

// ---------------- MFMA split GEMM, fp32 inputs (fallback only) ----------------
template<int KDIM, int NDIM>
__global__ __launch_bounds__(256) void gemm_mfma_split(
    const float* __restrict__ A, const float* __restrict__ B,
    const float* __restrict__ bias, float* __restrict__ C, int M)
{
    constexpr int LS = 40;
    __shared__ unsigned short Ah[128*LS], Al[128*LS], Bh[128*LS], Bl[128*LS];
    const int n0 = blockIdx.x*128, m0 = blockIdx.y*128;
    const int tid  = threadIdx.x;
    const int lane = tid & 63, wid = tid >> 6;
    const int wm = wid >> 1, wn = wid & 1;
    const int srow = tid >> 1, sk = (tid & 1)*16;
    f32x4 acc[4][4] = {};

    for (int k0 = 0; k0 < KDIM; k0 += 32){
        __syncthreads();
        {
            int ar = m0 + srow;
            float xv[16];
            if (ar < M){
                const float4* ap = reinterpret_cast<const float4*>(A + (size_t)ar*KDIM + k0 + sk);
                #pragma unroll
                for (int q = 0; q < 4; q++){
                    float4 v = ap[q];
                    xv[q*4+0]=v.x; xv[q*4+1]=v.y; xv[q*4+2]=v.z; xv[q*4+3]=v.w;
                }
            } else {
                #pragma unroll
                for (int q = 0; q < 16; q++) xv[q] = 0.f;
            }
            #pragma unroll
            for (int q = 0; q < 16; q++){
                unsigned short h,l; split2(xv[q], h, l);
                Ah[srow*LS + sk + q] = h;
                Al[srow*LS + sk + q] = l;
            }
        }
        {
            int br = n0 + srow;
            const float4* bp = reinterpret_cast<const float4*>(B + (size_t)br*KDIM + k0 + sk);
            #pragma unroll
            for (int q = 0; q < 4; q++){
                float4 v = bp[q];
                float xs[4] = {v.x, v.y, v.z, v.w};
                #pragma unroll
                for (int j = 0; j < 4; j++){
                    unsigned short h,l; split2(xs[j], h, l);
                    Bh[srow*LS + sk + q*4 + j] = h;
                    Bl[srow*LS + sk + q*4 + j] = l;
                }
            }
        }
        __syncthreads();
        const int fr = lane & 15, fk = (lane >> 4)*8;
        short8 a_h[4], a_l[4], b_h[4], b_l[4];
        #pragma unroll
        for (int mi = 0; mi < 4; mi++){
            int row = wm*64 + mi*16 + fr;
            a_h[mi] = *reinterpret_cast<const short8*>(&Ah[row*LS + fk]);
            a_l[mi] = *reinterpret_cast<const short8*>(&Al[row*LS + fk]);
        }
        #pragma unroll
        for (int nj = 0; nj < 4; nj++){
            int rowb = wn*64 + nj*16 + fr;
            b_h[nj] = *reinterpret_cast<const short8*>(&Bh[rowb*LS + fk]);
            b_l[nj] = *reinterpret_cast<const short8*>(&Bl[rowb*LS + fk]);
        }
        #pragma unroll
        for (int mi = 0; mi < 4; mi++)
            #pragma unroll
            for (int nj = 0; nj < 4; nj++){
                acc[mi][nj] = __builtin_amdgcn_mfma_f32_16x16x32_bf16(a_h[mi], b_h[nj], acc[mi][nj], 0,0,0);
                acc[mi][nj] = __builtin_amdgcn_mfma_f32_16x16x32_bf16(a_h[mi], b_l[nj], acc[mi][nj], 0,0,0);
                acc[mi][nj] = __builtin_amdgcn_mfma_f32_16x16x32_bf16(a_l[mi], b_h[nj], acc[mi][nj], 0,0,0);
            }
    }
    const int fr = lane & 15, fq = lane >> 4;
    #pragma unroll
    for (int nj = 0; nj < 4; nj++){
        int col = n0 + wn*64 + nj*16 + fr;
        float bv = bias[col];
        #pragma unroll
        for (int mi = 0; mi < 4; mi++){
            int rbase = m0 + wm*64 + mi*16 + fq*4;
            #pragma unroll
            for (int j = 0; j < 4; j++){
                int row = rbase + j;
                if (row < M)
                    __builtin_nontemporal_store(acc[mi][nj][j] + bv, &C[(size_t)row*NDIM + col]);
            }
        }
    }
}

// ---- global_load_lds width-16 helper (size must be a literal) ----
__device__ __forceinline__ void gll16(const unsigned short* g, unsigned short* l){
    __builtin_amdgcn_global_load_lds(
        (const __attribute__((address_space(1))) unsigned int*)g,
        (__attribute__((address_space(3))) unsigned int*)l, 16, 0, 0);
}

// ---------------- plane GEMM, m97 structure, n-fastest XCD chunking (round-13 cfg) ----------------
// lid = m_tile*NTN + n_tile (N fastest): XCD chunk = contiguous lids = same-m blocks
// -> A panel L2-resident per XCD (the configuration measured faster in r13 vs r14).
// PASSES=3: C = AhBh + AhBl + AlBh (near-fp32). PASSES=2: C = (Ah+Al)Bh -- B quantized
// to bf16; err ~1e-4 (< 1 bf16 ULP of |out|max) -- used ONLY for the final projection.
// PASSES=2 stages 3 planes (24KB LDS), wave 3 idles during staging.
template<int KDIM, int NDIM, int NTN, int PASSES>
__global__ __launch_bounds__(256) void gemm_planes_gll(
    const unsigned short* __restrict__ Ahi, const unsigned short* __restrict__ Alo,
    const unsigned short* __restrict__ Bhi, const unsigned short* __restrict__ Blo,
    const float* __restrict__ bias, float* __restrict__ C, int M)
{
    constexpr int NP = (PASSES == 3) ? 4 : 3;
    __shared__ unsigned short P[NP][128*32];
    const int total = gridDim.x;
    const int q = total >> 3, r8 = total & 7;
    const int xcd = blockIdx.x & 7, idx = blockIdx.x >> 3;
    const int lid = (xcd < r8 ? xcd*(q+1) : r8*(q+1) + (xcd - r8)*q) + idx;
    const int m0 = (lid / NTN)*128, n0 = (lid % NTN)*128;

    const int tid  = threadIdx.x;
    const int lane = tid & 63, wid = tid >> 6;
    const int wm = wid >> 1, wn = wid & 1;

    const bool stager = (PASSES == 3) || (wid < 3);
    const unsigned short* gsrc = (wid == 0) ? Ahi : (wid == 1) ? Alo
                               : (wid == 2) ? Bhi : Blo;
    const int row0 = (wid < 2) ? m0 : n0;
    const unsigned short* gbase = gsrc + (size_t)(row0 + (lane >> 2))*KDIM
                                       + 8*((lane & 3) ^ ((lane >> 3) & 3));
    unsigned short* lbase = &P[(wid < NP) ? wid : 0][0];

    f32x4 acc[4][4] = {};

    for (int k0 = 0; k0 < KDIM; k0 += 32){
        __syncthreads();
        if (stager){
            #pragma unroll
            for (int i = 0; i < 8; i++)
                gll16(gbase + k0 + (size_t)i*16*KDIM, lbase + i*512);
        }
        __syncthreads();

        const int fr = lane & 15, fkq = lane >> 4;
        const int swz = 8*(fkq ^ ((fr >> 1) & 3));
        short8 a_h[4], a_l[4], b_h[4], b_l[4];
        #pragma unroll
        for (int mi = 0; mi < 4; mi++){
            int row = wm*64 + mi*16 + fr;
            a_h[mi] = *reinterpret_cast<const short8*>(&P[0][row*32 + swz]);
            a_l[mi] = *reinterpret_cast<const short8*>(&P[1][row*32 + swz]);
        }
        #pragma unroll
        for (int nj = 0; nj < 4; nj++){
            int row = wn*64 + nj*16 + fr;
            b_h[nj] = *reinterpret_cast<const short8*>(&P[2][row*32 + swz]);
            if (PASSES == 3)
                b_l[nj] = *reinterpret_cast<const short8*>(&P[NP-1][row*32 + swz]);
        }
        #pragma unroll
        for (int mi = 0; mi < 4; mi++)
            #pragma unroll
            for (int nj = 0; nj < 4; nj++){
                acc[mi][nj] = __builtin_amdgcn_mfma_f32_16x16x32_bf16(a_h[mi], b_h[nj], acc[mi][nj], 0,0,0);
                acc[mi][nj] = __builtin_amdgcn_mfma_f32_16x16x32_bf16(a_l[mi], b_h[nj], acc[mi][nj], 0,0,0);
                if (PASSES == 3)
                    acc[mi][nj] = __builtin_amdgcn_mfma_f32_16x16x32_bf16(a_h[mi], b_l[nj], acc[mi][nj], 0,0,0);
            }
    }
    const int fr = lane & 15, fq = lane >> 4;
    #pragma unroll
    for (int nj = 0; nj < 4; nj++){
        int col = n0 + wn*64 + nj*16 + fr;
        float bv = bias[col];
        #pragma unroll
        for (int mi = 0; mi < 4; mi++){
            int rbase = m0 + wm*64 + mi*16 + fq*4;
            #pragma unroll
            for (int j = 0; j < 4; j++){
                int row = rbase + j;
                if (row < M)
                    __builtin_nontemporal_store(acc[mi][nj][j] + bv, &C[(size_t)row*NDIM + col]);
            }
        }
    }
}

// ---------------- persistent LSTM layer body (weights in VGPR MFMA fragments) ----------------
__device__ __forceinline__ void lstm_body(
    const float* __restrict__ Xp, const float* __restrict__ Whh,
    const float* __restrict__ hinit, const float* __restrict__ cinit,
    float* __restrict__ ys, float* __restrict__ cfin,
    int T, unsigned* __restrict__ flagbase, int bx)
{
    constexpr int WS = 520;
    __shared__ unsigned short hH[8*WS], hL[8*WS];     // 16.6 KB
    __shared__ float red[2048 + 128];                 // 8.7 KB
    __shared__ unsigned short zbuf[8];

    const int hc  = bx & 31, bc = bx >> 5;
    const int hid0 = hc*16;
    const int tid = threadIdx.x;
    const int lane = tid & 63, kc = tid >> 6;
    const int fr = lane & 15, fkq = lane >> 4;
    unsigned* myflag = flagbase + (size_t)(bc*32 + hc)*16;

    if (tid < 8) zbuf[tid] = 0;

    // ---- Whh -> per-lane register fragments (once; loop-invariant) ----
    short8 ah[4][4], al[4][4];
    #pragma unroll
    for (int m = 0; m < 4; m++){
        const float* wr = Whh + (size_t)(m*HID + hid0 + fr)*HID;
        #pragma unroll
        for (int s = 0; s < 4; s++){
            int k0 = kc*128 + s*32 + fkq*8;
            f32x4 v0 = *reinterpret_cast<const f32x4*>(wr + k0);
            f32x4 v1 = *reinterpret_cast<const f32x4*>(wr + k0 + 4);
            short8 h8, l8;
            float xv[8] = {v0[0],v0[1],v0[2],v0[3],v1[0],v1[1],v1[2],v1[3]};
            #pragma unroll
            for (int j = 0; j < 8; j++){
                unsigned short hh, ll; split2(xv[j], hh, ll);
                h8[j] = (short)hh; l8[j] = (short)ll;
            }
            ah[m][s] = h8; al[m][s] = l8;
        }
    }

    const int ub = tid >> 4;
    const int uh = tid & 15;
    float creg = 0.f;
    if (tid < 128) creg = cinit[(size_t)(bc*8 + ub)*HID + hid0 + uh];

    const size_t hbase = (size_t)bc*8*HID;
    const float* xprow = Xp + (size_t)(bc*8 + ub)*G4 + hid0 + uh;

    float xn0=0.f, xn1=0.f, xn2=0.f, xn3=0.f;
    if (tid < 128){
        const float* xpr = xprow;
        xn0 = xpr[0]; xn1 = xpr[512]; xn2 = xpr[1024]; xn3 = xpr[1536];
    }

    for (int t = 0; t < T; t++){
        // ---- stage h(t-1): cached fp32 loads -> bf16 hi/lo LDS ----
        {
            const f32x4* hsrc = reinterpret_cast<const f32x4*>(
                (t == 0) ? (hinit + hbase) : (ys + (size_t)(t-1)*BATCH*HID + hbase));
            #pragma unroll
            for (int j = 0; j < 4; j++){
                int fidx = tid + j*256;
                f32x4 v = hsrc[fidx];
                int e   = fidx*4;
                int row = e >> 9, col = e & 511;
                ush4 h, l;
                #pragma unroll
                for (int qq = 0; qq < 4; qq++){ unsigned short a,b; split2(v[qq], a, b); h[qq]=a; l[qq]=b; }
                *reinterpret_cast<ush4*>(&hH[row*WS + col]) = h;
                *reinterpret_cast<ush4*>(&hL[row*WS + col]) = l;
            }
        }
        __syncthreads();

        // ---- MFMA partial dots (weights from registers, h from LDS) ----
        {
            f32x4 acc4[4] = {};
            const bool breal = fr < 8;
            #pragma unroll
            for (int s = 0; s < 4; s++){
                int k0 = kc*128 + s*32 + fkq*8;
                short8 bh = breal ? *reinterpret_cast<const short8*>(&hH[fr*WS + k0])
                                  : *reinterpret_cast<const short8*>(zbuf);
                short8 bl = breal ? *reinterpret_cast<const short8*>(&hL[fr*WS + k0])
                                  : *reinterpret_cast<const short8*>(zbuf);
                #pragma unroll
                for (int m = 0; m < 4; m++){
                    acc4[m] = __builtin_amdgcn_mfma_f32_16x16x32_bf16(ah[m][s], bh, acc4[m], 0,0,0);
                    acc4[m] = __builtin_amdgcn_mfma_f32_16x16x32_bf16(ah[m][s], bl, acc4[m], 0,0,0);
                    acc4[m] = __builtin_amdgcn_mfma_f32_16x16x32_bf16(al[m][s], bh, acc4[m], 0,0,0);
                }
            }
            const int b = lane & 15;
            if (b < 8){
                #pragma unroll
                for (int m = 0; m < 4; m++)
                    #pragma unroll
                    for (int qq = 0; qq < 4; qq++){
                        int rowp = m*16 + (lane >> 4)*4 + qq;
                        red[kc*512 + rowp*8 + b] = acc4[m][qq];
                    }
            }
        }
        __syncthreads();

        if (tid < 64){
            #pragma unroll
            for (int b = 0; b < 8; b++)
                red[tid*8 + b] = red[tid*8 + b] + red[512 + tid*8 + b]
                               + red[1024 + tid*8 + b] + red[1536 + tid*8 + b];
        }
        __syncthreads();

        if (tid < 128){
            float gi = red[(0*16 + uh)*8 + ub] + xn0;
            float gf = red[(1*16 + uh)*8 + ub] + xn1;
            float gg = red[(2*16 + uh)*8 + ub] + xn2;
            float go = red[(3*16 + uh)*8 + ub] + xn3;
            float si = 1.f/(1.f + expf(-gi));
            float sf = 1.f/(1.f + expf(-gf));
            float so = 1.f/(1.f + expf(-go));
            float tg = tanhf(gg);
            float c = sf*creg + si*tg;
            creg = c;
            red[2048 + tid] = so * tanhf(c);
            if (t < T-1){
                const float* xpr = xprow + (size_t)(t+1)*BATCH*G4;
                xn0 = xpr[0]; xn1 = xpr[512]; xn2 = xpr[1024]; xn3 = xpr[1536];
            }
        }
        __syncthreads();

        if (tid < 64){
            if (tid < 32){
                f32x4 v = *reinterpret_cast<const f32x4*>(&red[2048 + tid*4]);
                const f32x4* addr = reinterpret_cast<const f32x4*>(
                    ys + (size_t)t*BATCH*HID
                       + (size_t)(bc*8 + (tid >> 2))*HID + hid0 + (tid & 3)*4);
                asm volatile("global_store_dwordx4 %0, %1, off sc0 sc1"
                             :: "v"(addr), "v"(v) : "memory");
            }
            if (t < T-1){
                asm volatile("s_waitcnt vmcnt(0)" ::: "memory");
                if (tid == 0)
                    __hip_atomic_store(myflag, (unsigned)(t+1),
                                       __ATOMIC_RELAXED, __HIP_MEMORY_SCOPE_AGENT);
                const unsigned tgt = (unsigned)(t+1);
                unsigned* fp = flagbase + (size_t)(bc*32 + (tid & 31))*16;
                unsigned spins = 0;
                bool done = false;
                while (!done && spins < (1u<<20)){
                    unsigned v = tgt;
                    if (tid < 32)
                        v = __hip_atomic_load(fp, __ATOMIC_RELAXED, __HIP_MEMORY_SCOPE_AGENT);
                    done = (bool)__all((int)(v >= tgt));
                    spins++;
                }
            }
        }
        __syncthreads();
    }

    if (tid < 128)
        cfin[(size_t)(bc*8 + ub)*HID + hid0 + uh] = creg;
}

__global__ __launch_bounds__(256, 2) void lstm_layer_k(
    const float* Xp, const float* Whh, const float* hinit, const float* cinit,
    float* ys, float* cfin, int T, unsigned* flagbase)
{
    lstm_body(Xp, Whh, hinit, cinit, ys, cfin, T, flagbase, blockIdx.x);
}

__global__ __launch_bounds__(256, 2) void lstm_dual_k(
    const float* Xp0, const float* Whh0, const float* hi0, const float* ci0,
    float* ys0, float* cf0, int T0, unsigned* fl0,
    const float* Xp1, const float* Whh1, const float* hi1, const float* ci1,
    float* ys1, float* cf1, int T1, unsigned* fl1)
{
    const int role = blockIdx.x >> 8;
    const int bx = blockIdx.x & 255;
    const float* Xp   = role ? Xp1 : Xp0;
    const float* Whh  = role ? Whh1 : Whh0;
    const float* hi   = role ? hi1 : hi0;
    const float* ci   = role ? ci1 : ci0;
    float* ys         = role ? ys1 : ys0;
    float* cf         = role ? cf1 : cf0;
    int T             = role ? T1 : T0;
    unsigned* fl      = role ? fl1 : fl0;
    lstm_body(Xp, Whh, hi, ci, ys, cf, T, fl, bx);
}

extern "C" void kernel_launch(void* const* d_in, const int* in_sizes, int n_in,
                              void* d_out, int out_size, void* d_ws, size_t ws_size,
                              hipStream_t stream) {
    const int*   src      = (const int*)  d_in[0];
    const int*   trg      = (const int*)  d_in[1];
    const float* enc_emb  = (const float*)d_in[2];
    const float* enc_Wih0 = (const float*)d_in[3];
    const float* enc_Whh0 = (const float*)d_in[4];
    const float* enc_b0   = (const float*)d_in[5];
    const float* enc_Wih1 = (const float*)d_in[6];
    const float* enc_Whh1 = (const float*)d_in[7];
    const float* enc_b1   = (const float*)d_in[8];
    const float* dec_emb  = (const float*)d_in[9];
    const float* dec_Wih0 = (const float*)d_in[10];
    const float* dec_Whh0 = (const float*)d_in[11];
    const float* dec_b0   = (const float*)d_in[12];
    const float* dec_Wih1 = (const float*)d_in[13];
    const float* dec_Whh1 = (const float*)d_in[14];
    const float* dec_b1   = (const float*)d_in[15];
    const float* out_W    = (const float*)d_in[16];
    const float* out_b    = (const float*)d_in[17];

    // Big transient scratch in d_out (fp32, 100.35M elems); all dead before final GEMM.
    float* ob = (float*)d_out;
    float* Xp   = ob;                         // [3200,2048]
    float* xe   = ob + (size_t)6553600;       // [3200,256]
    float* xd   = ob + (size_t)7372800;       // [3136,256]
    float* eys0 = ob + (size_t)8175616;       // [50*64,512]
    float* eys1 = ob + (size_t)9814016;       // [50*64,512]
    float* dys0 = ob + (size_t)11452416;      // [49*64,512]
    float* Xp2  = ob + (size_t)13058048;      // [3136,2048]

    // d_ws layout (unchanged from round 13/14).
    float* ws = (float*)d_ws;
    float* dys1 = ws;                              // [49*64,512]
    float* c0   = ws + (size_t)1605632;
    float* c1   = ws + (size_t)1638400;
    float* hz   = ws + (size_t)1671168;
    unsigned* flags = (unsigned*)(ws + (size_t)1703936); // 16384 uints
    unsigned short* Whi = (unsigned short*)(ws + (size_t)1720320);
    unsigned short* Wlo = Whi + (size_t)16384000;  // unused in 2-pass mode
    unsigned short* Ahi = Wlo + (size_t)16384000;
    unsigned short* Alo = Ahi + (size_t)1638400;   // 3200*512 (padded rows)
    unsigned short* eW0h = Alo  + (size_t)1638400;
    unsigned short* eW0l = eW0h + (size_t)524288;
    unsigned short* eW1h = eW0l + (size_t)524288;
    unsigned short* eW1l = eW1h + (size_t)1048576;
    unsigned short* dW0h = eW1l + (size_t)1048576;
    unsigned short* dW0l = dW0h + (size_t)524288;
    unsigned short* dW1h = dW0l + (size_t)524288;
    unsigned short* dW1l = dW1h + (size_t)1048576;
    unsigned short* XAh  = dW1l + (size_t)1048576;
    unsigned short* XAl  = XAh  + (size_t)1638400;
    const size_t end_final = (size_t)1720320*4 + ((size_t)16384000 + 1638400)*2*2;
    const size_t end_xp    = end_final + ((size_t)6291456 + 3276800)*2;
    const bool planes_ok = (ws_size >= end_final);
    const bool xp_ok     = (ws_size >= end_xp);

    // zero c0,c1,hz + flags
    {
        int n = 3*BATCH*HID + 4*4096;
        zero_kernel<<<(n+255)/256, 256, 0, stream>>>(c0, n);
    }

    if (planes_ok)   // hi-only: final GEMM is 2-pass, Wlo unused
        split_hi_kernel<<<(16384000/4 + 255)/256, 256, 0, stream>>>(out_W, Whi, 16384000/4);
    if (xp_ok){
        split_kernel<<<(524288/4 + 255)/256, 256, 0, stream>>>(enc_Wih0, eW0h, eW0l, 524288/4);
        split_kernel<<<(1048576/4 + 255)/256, 256, 0, stream>>>(enc_Wih1, eW1h, eW1l, 1048576/4);
        split_kernel<<<(524288/4 + 255)/256, 256, 0, stream>>>(dec_Wih0, dW0h, dW0l, 524288/4);
        split_kernel<<<(1048576/4 + 255)/256, 256, 0, stream>>>(dec_Wih1, dW1h, dW1l, 1048576/4);
    }

    // embeddings
    embed_kernel<<<(50*BATCH*(EMB/4)+255)/256, 256, 0, stream>>>(src, enc_emb, xe, 50);
    embed_kernel<<<(49*BATCH*(EMB/4)+255)/256, 256, 0, stream>>>(trg, dec_emb, xd, 49);

    dim3 xgrid(G4/128, 25);   // fallback grid

    // ---- encoder layer 0 ----
    if (xp_ok){
        split_kernel<<<(819200/4 + 255)/256, 256, 0, stream>>>(xe, XAh, XAl, 819200/4);
        gemm_planes_gll<EMB, G4, 16, 3><<<400, 256, 0, stream>>>(XAh, XAl, eW0h, eW0l, enc_b0, Xp, 3200);
    } else
        gemm_mfma_split<EMB, G4><<<xgrid, 256, 0, stream>>>(xe, enc_Wih0, enc_b0, Xp, 3200);
    lstm_layer_k<<<256, 256, 0, stream>>>(Xp, enc_Whh0, hz, hz, eys0, c0, 50, flags + 0);

    // ---- Xp for encoder layer 1 (from eys0) and decoder layer 0 (from xd) ----
    if (xp_ok){
        split_kernel<<<(1638400/4 + 255)/256, 256, 0, stream>>>(eys0, XAh, XAl, 1638400/4);
        gemm_planes_gll<HID, G4, 16, 3><<<400, 256, 0, stream>>>(XAh, XAl, eW1h, eW1l, enc_b1, Xp, 3200);
        split_kernel<<<(802816/4 + 255)/256, 256, 0, stream>>>(xd, XAh, XAl, 802816/4);
        gemm_planes_gll<EMB, G4, 16, 3><<<400, 256, 0, stream>>>(XAh, XAl, dW0h, dW0l, dec_b0, Xp2, 3136);
    } else {
        gemm_mfma_split<HID, G4><<<xgrid, 256, 0, stream>>>(eys0, enc_Wih1, enc_b1, Xp, 3200);
        gemm_mfma_split<EMB, G4><<<xgrid, 256, 0, stream>>>(xd, dec_Wih0, dec_b0, Xp2, 3136);
    }

    // ---- encoder layer 1 AND decoder layer 0 CONCURRENTLY (independent) ----
    lstm_dual_k<<<512, 256, 0, stream>>>(
        Xp,  enc_Whh1, hz,                            hz, eys1, c1, 50, flags + 4096,
        Xp2, dec_Whh0, eys0 + (size_t)49*BATCH*HID,   c0, dys0, c0, 49, flags + 8192);

    // ---- decoder layer 1 ----
    if (xp_ok){
        split_kernel<<<(1605632/4 + 255)/256, 256, 0, stream>>>(dys0, XAh, XAl, 1605632/4);
        gemm_planes_gll<HID, G4, 16, 3><<<400, 256, 0, stream>>>(XAh, XAl, dW1h, dW1l, dec_b1, Xp, 3136);
    } else
        gemm_mfma_split<HID, G4><<<xgrid, 256, 0, stream>>>(dys0, dec_Wih1, dec_b1, Xp, 3136);
    lstm_layer_k<<<256, 256, 0, stream>>>(Xp, dec_Whh1, eys1 + (size_t)49*BATCH*HID, c1,
                                          dys1, c1, 49, flags + 12288);

    // ---- final projection -> fp32 d_out [3136, 32000]: 2-pass, n-fastest ----
    if (planes_ok){
        split_kernel<<<(1605632/4 + 255)/256, 256, 0, stream>>>(dys1, Ahi, Alo, 1605632/4);
        gemm_planes_gll<HID, VOCAB, 250, 2><<<6250, 256, 0, stream>>>(
            Ahi, Alo, Whi, Whi, out_b, (float*)d_out, 3136);
    } else {
        gemm_mfma_split<HID, VOCAB><<<dim3(VOCAB/128, 25), 256, 0, stream>>>(
            dys1, out_W, out_b, (float*)d_out, 3136);
    }
}

// Round 16
// 952.943 us; speedup vs baseline: 1.4837x; 1.0675x over previous
//
#include <hip/hip_runtime.h>
#include <hip/hip_bf16.h>

#define BATCH 64
#define HID 512
#define EMB 256
#define VOCAB 32000
#define G4 2048   // 4*HID

typedef __attribute__((ext_vector_type(8))) short short8;
typedef __attribute__((ext_vector_type(4))) float f32x4;
typedef __attribute__((ext_vector_type(4))) unsigned short ush4;

// ---------------- zero init ----------------
__global__ __launch_bounds__(256) void zero_kernel(float* p, int n){
    int i = blockIdx.x*256 + threadIdx.x;
    if (i < n) p[i] = 0.f;
}

// round-to-nearest-even fp32 -> bf16 bits
__device__ __forceinline__ unsigned short bf16_rne(float x){
    unsigned b = __float_as_uint(x);
    return (unsigned short)((b + 0x7fffu + ((b >> 16) & 1u)) >> 16);
}
__device__ __forceinline__ void split2(float x, unsigned short& h, unsigned short& l){
    h = bf16_rne(x);
    l = bf16_rne(x - __uint_as_float((unsigned)h << 16));
}

// ---------------- embedding gather (fp32, fallback path) ----------------
__global__ __launch_bounds__(256) void embed_kernel(const int* __restrict__ tok,
                                                    const float* __restrict__ emb,
                                                    float* __restrict__ out, int T){
    int i = blockIdx.x*256 + threadIdx.x;
    int n = T*BATCH*(EMB/4);
    if (i >= n) return;
    int e4 = i % (EMB/4);
    int tb = i / (EMB/4);
    int id = tok[tb];
    reinterpret_cast<float4*>(out)[(size_t)tb*(EMB/4) + e4] =
        reinterpret_cast<const float4*>(emb + (size_t)id*EMB)[e4];
}

// ---------------- embedding gather straight into bf16 hi/lo planes ----------------
__global__ __launch_bounds__(256) void embed_plane_kernel(const int* __restrict__ tok,
                                                          const float* __restrict__ emb,
                                                          unsigned short* __restrict__ hi,
                                                          unsigned short* __restrict__ lo, int T){
    int i = blockIdx.x*256 + threadIdx.x;
    int n = T*BATCH*(EMB/4);
    if (i >= n) return;
    int e4 = i % (EMB/4);
    int tb = i / (EMB/4);
    int id = tok[tb];
    f32x4 v = reinterpret_cast<const f32x4*>(emb + (size_t)id*EMB)[e4];
    ush4 h, l;
    #pragma unroll
    for (int j = 0; j < 4; j++){ unsigned short a,b; split2(v[j], a, b); h[j]=a; l[j]=b; }
    reinterpret_cast<ush4*>(hi)[(size_t)tb*(EMB/4) + e4] = h;
    reinterpret_cast<ush4*>(lo)[(size_t)tb*(EMB/4) + e4] = l;
}

// ---------------- fp32 -> bf16 hi/lo plane split ----------------
__global__ __launch_bounds__(256) void split_kernel(const float* __restrict__ in,
                                                    unsigned short* __restrict__ hi,
                                                    unsigned short* __restrict__ lo, int n4){
    int i = blockIdx.x*256 + threadIdx.x;
    if (i >= n4) return;
    f32x4 v = reinterpret_cast<const f32x4*>(in)[i];
    ush4 h, l;
    #pragma unroll
    for (int j = 0; j < 4; j++){ unsigned short a,b; split2(v[j], a, b); h[j]=a; l[j]=b; }
    reinterpret_cast<ush4*>(hi)[i] = h;
    reinterpret_cast<ush4*>(lo)[i] = l;
}

// hi-only split (final GEMM B)
__global__ __launch_bounds__(256) void split_hi_kernel(const float* __restrict__ in,
                                                       unsigned short* __restrict__ hi, int n4){
    int i = blockIdx.x*256 + threadIdx.x;
    if (i >= n4) return;
    f32x4 v = reinterpret_cast<const f32x4*>(in)[i];
    ush4 h;
    #pragma unroll
    for (int j = 0; j < 4; j++) h[j] = bf16_rne(v[j]);
    reinterpret_cast<ush4*>(hi)[i] = h;
}

// ---------------- MFMA split GEMM, fp32 inputs (fallback only) ----------------
template<int KDIM, int NDIM>
__global__ __launch_bounds__(256) void gemm_mfma_split(
    const float* __restrict__ A, const float* __restrict__ B,
    const float* __restrict__ bias, float* __restrict__ C, int M)
{
    constexpr int LS = 40;
    __shared__ unsigned short Ah[128*LS], Al[128*LS], Bh[128*LS], Bl[128*LS];
    const int n0 = blockIdx.x*128, m0 = blockIdx.y*128;
    const int tid  = threadIdx.x;
    const int lane = tid & 63, wid = tid >> 6;
    const int wm = wid >> 1, wn = wid & 1;
    const int srow = tid >> 1, sk = (tid & 1)*16;
    f32x4 acc[4][4] = {};

    for (int k0 = 0; k0 < KDIM; k0 += 32){
        __syncthreads();
        {
            int ar = m0 + srow;
            float xv[16];
            if (ar < M){
                const float4* ap = reinterpret_cast<const float4*>(A + (size_t)ar*KDIM + k0 + sk);
                #pragma unroll
                for (int q = 0; q < 4; q++){
                    float4 v = ap[q];
                    xv[q*4+0]=v.x; xv[q*4+1]=v.y; xv[q*4+2]=v.z; xv[q*4+3]=v.w;
                }
            } else {
                #pragma unroll
                for (int q = 0; q < 16; q++) xv[q] = 0.f;
            }
            #pragma unroll
            for (int q = 0; q < 16; q++){
                unsigned short h,l; split2(xv[q], h, l);
                Ah[srow*LS + sk + q] = h;
                Al[srow*LS + sk + q] = l;
            }
        }
        {
            int br = n0 + srow;
            const float4* bp = reinterpret_cast<const float4*>(B + (size_t)br*KDIM + k0 + sk);
            #pragma unroll
            for (int q = 0; q < 4; q++){
                float4 v = bp[q];
                float xs[4] = {v.x, v.y, v.z, v.w};
                #pragma unroll
                for (int j = 0; j < 4; j++){
                    unsigned short h,l; split2(xs[j], h, l);
                    Bh[srow*LS + sk + q*4 + j] = h;
                    Bl[srow*LS + sk + q*4 + j] = l;
                }
            }
        }
        __syncthreads();
        const int fr = lane & 15, fk = (lane >> 4)*8;
        short8 a_h[4], a_l[4], b_h[4], b_l[4];
        #pragma unroll
        for (int mi = 0; mi < 4; mi++){
            int row = wm*64 + mi*16 + fr;
            a_h[mi] = *reinterpret_cast<const short8*>(&Ah[row*LS + fk]);
            a_l[mi] = *reinterpret_cast<const short8*>(&Al[row*LS + fk]);
        }
        #pragma unroll
        for (int nj = 0; nj < 4; nj++){
            int rowb = wn*64 + nj*16 + fr;
            b_h[nj] = *reinterpret_cast<const short8*>(&Bh[rowb*LS + fk]);
            b_l[nj] = *reinterpret_cast<const short8*>(&Bl[rowb*LS + fk]);
        }
        #pragma unroll
        for (int mi = 0; mi < 4; mi++)
            #pragma unroll
            for (int nj = 0; nj < 4; nj++){
                acc[mi][nj] = __builtin_amdgcn_mfma_f32_16x16x32_bf16(a_h[mi], b_h[nj], acc[mi][nj], 0,0,0);
                acc[mi][nj] = __builtin_amdgcn_mfma_f32_16x16x32_bf16(a_h[mi], b_l[nj], acc[mi][nj], 0,0,0);
                acc[mi][nj] = __builtin_amdgcn_mfma_f32_16x16x32_bf16(a_l[mi], b_h[nj], acc[mi][nj], 0,0,0);
            }
    }
    const int fr = lane & 15, fq = lane >> 4;
    #pragma unroll
    for (int nj = 0; nj < 4; nj++){
        int col = n0 + wn*64 + nj*16 + fr;
        float bv = bias[col];
        #pragma unroll
        for (int mi = 0; mi < 4; mi++){
            int rbase = m0 + wm*64 + mi*16 + fq*4;
            #pragma unroll
            for (int j = 0; j < 4; j++){
                int row = rbase + j;
                if (row < M)
                    __builtin_nontemporal_store(acc[mi][nj][j] + bv, &C[(size_t)row*NDIM + col]);
            }
        }
    }
}

// ---- global_load_lds width-16 helper (size must be a literal) ----
__device__ __forceinline__ void gll16(const unsigned short* g, unsigned short* l){
    __builtin_amdgcn_global_load_lds(
        (const __attribute__((address_space(1))) unsigned int*)g,
        (__attribute__((address_space(3))) unsigned int*)l, 16, 0, 0);
}

// ---------------- plane GEMM, m97 structure, n-fastest XCD chunking ----------------
// PASSES=3: C = AhBh + AlBh + AhBl (near-fp32, recurrent-path Xp GEMMs).
// PASSES=1: C = AhBh (both operands bf16; final projection only -- error sub-ULP
// at this output scale, measured: B-only quantization changed absmax by 0).
template<int KDIM, int NDIM, int NTN, int PASSES>
__global__ __launch_bounds__(256) void gemm_planes_gll(
    const unsigned short* __restrict__ Ahi, const unsigned short* __restrict__ Alo,
    const unsigned short* __restrict__ Bhi, const unsigned short* __restrict__ Blo,
    const float* __restrict__ bias, float* __restrict__ C, int M)
{
    constexpr int NP = (PASSES == 3) ? 4 : 2;
    __shared__ unsigned short P[NP][128*32];
    const int total = gridDim.x;
    const int q = total >> 3, r8 = total & 7;
    const int xcd = blockIdx.x & 7, idx = blockIdx.x >> 3;
    const int lid = (xcd < r8 ? xcd*(q+1) : r8*(q+1) + (xcd - r8)*q) + idx;
    const int m0 = (lid / NTN)*128, n0 = (lid % NTN)*128;

    const int tid  = threadIdx.x;
    const int lane = tid & 63, wid = tid >> 6;
    const int wm = wid >> 1, wn = wid & 1;

    const unsigned short* gsrc;
    int row0;
    bool stager;
    if (PASSES == 3){
        gsrc = (wid == 0) ? Ahi : (wid == 1) ? Alo : (wid == 2) ? Bhi : Blo;
        row0 = (wid < 2) ? m0 : n0;
        stager = true;
    } else {
        gsrc = (wid == 0) ? Ahi : Bhi;
        row0 = (wid == 0) ? m0 : n0;
        stager = (wid < 2);
    }
    const unsigned short* gbase = gsrc + (size_t)(row0 + (lane >> 2))*KDIM
                                       + 8*((lane & 3) ^ ((lane >> 3) & 3));
    unsigned short* lbase = &P[(wid < NP) ? wid : 0][0];

    f32x4 acc[4][4] = {};

    for (int k0 = 0; k0 < KDIM; k0 += 32){
        __syncthreads();
        if (stager){
            #pragma unroll
            for (int i = 0; i < 8; i++)
                gll16(gbase + k0 + (size_t)i*16*KDIM, lbase + i*512);
        }
        __syncthreads();

        const int fr = lane & 15, fkq = lane >> 4;
        const int swz = 8*(fkq ^ ((fr >> 1) & 3));
        constexpr int BHP = (PASSES == 3) ? 2 : 1;
        short8 a_h[4], a_l[4], b_h[4], b_l[4];
        #pragma unroll
        for (int mi = 0; mi < 4; mi++){
            int row = wm*64 + mi*16 + fr;
            a_h[mi] = *reinterpret_cast<const short8*>(&P[0][row*32 + swz]);
            if (PASSES == 3)
                a_l[mi] = *reinterpret_cast<const short8*>(&P[1][row*32 + swz]);
        }
        #pragma unroll
        for (int nj = 0; nj < 4; nj++){
            int row = wn*64 + nj*16 + fr;
            b_h[nj] = *reinterpret_cast<const short8*>(&P[BHP][row*32 + swz]);
            if (PASSES == 3)
                b_l[nj] = *reinterpret_cast<const short8*>(&P[3][row*32 + swz]);
        }
        #pragma unroll
        for (int mi = 0; mi < 4; mi++)
            #pragma unroll
            for (int nj = 0; nj < 4; nj++){
                acc[mi][nj] = __builtin_amdgcn_mfma_f32_16x16x32_bf16(a_h[mi], b_h[nj], acc[mi][nj], 0,0,0);
                if (PASSES == 3){
                    acc[mi][nj] = __builtin_amdgcn_mfma_f32_16x16x32_bf16(a_l[mi], b_h[nj], acc[mi][nj], 0,0,0);
                    acc[mi][nj] = __builtin_amdgcn_mfma_f32_16x16x32_bf16(a_h[mi], b_l[nj], acc[mi][nj], 0,0,0);
                }
            }
    }
    const int fr = lane & 15, fq = lane >> 4;
    #pragma unroll
    for (int nj = 0; nj < 4; nj++){
        int col = n0 + wn*64 + nj*16 + fr;
        float bv = bias[col];
        #pragma unroll
        for (int mi = 0; mi < 4; mi++){
            int rbase = m0 + wm*64 + mi*16 + fq*4;
            #pragma unroll
            for (int j = 0; j < 4; j++){
                int row = rbase + j;
                if (row < M)
                    __builtin_nontemporal_store(acc[mi][nj][j] + bv, &C[(size_t)row*NDIM + col]);
            }
        }
    }
}

// ---------------- persistent LSTM layer body ----------------
// Weights in VGPR MFMA fragments; optional direct bf16 hi/lo plane output of h
// (phi/plo) -- feeds the next GEMM's A planes, eliminating split kernels.
__device__ __forceinline__ void lstm_body(
    const float* __restrict__ Xp, const float* __restrict__ Whh,
    const float* __restrict__ hinit, const float* __restrict__ cinit,
    float* __restrict__ ys, float* __restrict__ cfin,
    int T, unsigned* __restrict__ flagbase, int bx,
    unsigned short* __restrict__ phi, unsigned short* __restrict__ plo)
{
    constexpr int WS = 520;
    __shared__ unsigned short hH[8*WS], hL[8*WS];     // 16.6 KB
    __shared__ float red[2048 + 128];                 // 8.7 KB
    __shared__ unsigned short zbuf[8];

    const int hc  = bx & 31, bc = bx >> 5;
    const int hid0 = hc*16;
    const int tid = threadIdx.x;
    const int lane = tid & 63, kc = tid >> 6;
    const int fr = lane & 15, fkq = lane >> 4;
    unsigned* myflag = flagbase + (size_t)(bc*32 + hc)*16;

    if (tid < 8) zbuf[tid] = 0;

    short8 ah[4][4], al[4][4];
    #pragma unroll
    for (int m = 0; m < 4; m++){
        const float* wr = Whh + (size_t)(m*HID + hid0 + fr)*HID;
        #pragma unroll
        for (int s = 0; s < 4; s++){
            int k0 = kc*128 + s*32 + fkq*8;
            f32x4 v0 = *reinterpret_cast<const f32x4*>(wr + k0);
            f32x4 v1 = *reinterpret_cast<const f32x4*>(wr + k0 + 4);
            short8 h8, l8;
            float xv[8] = {v0[0],v0[1],v0[2],v0[3],v1[0],v1[1],v1[2],v1[3]};
            #pragma unroll
            for (int j = 0; j < 8; j++){
                unsigned short hh, ll; split2(xv[j], hh, ll);
                h8[j] = (short)hh; l8[j] = (short)ll;
            }
            ah[m][s] = h8; al[m][s] = l8;
        }
    }

    const int ub = tid >> 4;
    const int uh = tid & 15;
    float creg = 0.f;
    if (tid < 128) creg = cinit[(size_t)(bc*8 + ub)*HID + hid0 + uh];

    const size_t hbase = (size_t)bc*8*HID;
    const float* xprow = Xp + (size_t)(bc*8 + ub)*G4 + hid0 + uh;

    float xn0=0.f, xn1=0.f, xn2=0.f, xn3=0.f;
    if (tid < 128){
        const float* xpr = xprow;
        xn0 = xpr[0]; xn1 = xpr[512]; xn2 = xpr[1024]; xn3 = xpr[1536];
    }

    for (int t = 0; t < T; t++){
        {
            const f32x4* hsrc = reinterpret_cast<const f32x4*>(
                (t == 0) ? (hinit + hbase) : (ys + (size_t)(t-1)*BATCH*HID + hbase));
            #pragma unroll
            for (int j = 0; j < 4; j++){
                int fidx = tid + j*256;
                f32x4 v = hsrc[fidx];
                int e   = fidx*4;
                int row = e >> 9, col = e & 511;
                ush4 h, l;
                #pragma unroll
                for (int qq = 0; qq < 4; qq++){ unsigned short a,b; split2(v[qq], a, b); h[qq]=a; l[qq]=b; }
                *reinterpret_cast<ush4*>(&hH[row*WS + col]) = h;
                *reinterpret_cast<ush4*>(&hL[row*WS + col]) = l;
            }
        }
        __syncthreads();

        {
            f32x4 acc4[4] = {};
            const bool breal = fr < 8;
            #pragma unroll
            for (int s = 0; s < 4; s++){
                int k0 = kc*128 + s*32 + fkq*8;
                short8 bh = breal ? *reinterpret_cast<const short8*>(&hH[fr*WS + k0])
                                  : *reinterpret_cast<const short8*>(zbuf);
                short8 bl = breal ? *reinterpret_cast<const short8*>(&hL[fr*WS + k0])
                                  : *reinterpret_cast<const short8*>(zbuf);
                #pragma unroll
                for (int m = 0; m < 4; m++){
                    acc4[m] = __builtin_amdgcn_mfma_f32_16x16x32_bf16(ah[m][s], bh, acc4[m], 0,0,0);
                    acc4[m] = __builtin_amdgcn_mfma_f32_16x16x32_bf16(ah[m][s], bl, acc4[m], 0,0,0);
                    acc4[m] = __builtin_amdgcn_mfma_f32_16x16x32_bf16(al[m][s], bh, acc4[m], 0,0,0);
                }
            }
            const int b = lane & 15;
            if (b < 8){
                #pragma unroll
                for (int m = 0; m < 4; m++)
                    #pragma unroll
                    for (int qq = 0; qq < 4; qq++){
                        int rowp = m*16 + (lane >> 4)*4 + qq;
                        red[kc*512 + rowp*8 + b] = acc4[m][qq];
                    }
            }
        }
        __syncthreads();

        if (tid < 64){
            #pragma unroll
            for (int b = 0; b < 8; b++)
                red[tid*8 + b] = red[tid*8 + b] + red[512 + tid*8 + b]
                               + red[1024 + tid*8 + b] + red[1536 + tid*8 + b];
        }
        __syncthreads();

        if (tid < 128){
            float gi = red[(0*16 + uh)*8 + ub] + xn0;
            float gf = red[(1*16 + uh)*8 + ub] + xn1;
            float gg = red[(2*16 + uh)*8 + ub] + xn2;
            float go = red[(3*16 + uh)*8 + ub] + xn3;
            float si = 1.f/(1.f + expf(-gi));
            float sf = 1.f/(1.f + expf(-gf));
            float so = 1.f/(1.f + expf(-go));
            float tg = tanhf(gg);
            float c = sf*creg + si*tg;
            creg = c;
            float hval = so * tanhf(c);
            red[2048 + tid] = hval;
            if (phi){   // direct bf16 hi/lo plane emission (next GEMM's A)
                unsigned short hh, ll; split2(hval, hh, ll);
                size_t poff = (size_t)t*BATCH*HID + (size_t)(bc*8 + ub)*HID + hid0 + uh;
                phi[poff] = hh; plo[poff] = ll;
            }
            if (t < T-1){
                const float* xpr = xprow + (size_t)(t+1)*BATCH*G4;
                xn0 = xpr[0]; xn1 = xpr[512]; xn2 = xpr[1024]; xn3 = xpr[1536];
            }
        }
        __syncthreads();

        if (tid < 64){
            if (tid < 32){
                f32x4 v = *reinterpret_cast<const f32x4*>(&red[2048 + tid*4]);
                const f32x4* addr = reinterpret_cast<const f32x4*>(
                    ys + (size_t)t*BATCH*HID
                       + (size_t)(bc*8 + (tid >> 2))*HID + hid0 + (tid & 3)*4);
                asm volatile("global_store_dwordx4 %0, %1, off sc0 sc1"
                             :: "v"(addr), "v"(v) : "memory");
            }
            if (t < T-1){
                asm volatile("s_waitcnt vmcnt(0)" ::: "memory");
                if (tid == 0)
                    __hip_atomic_store(myflag, (unsigned)(t+1),
                                       __ATOMIC_RELAXED, __HIP_MEMORY_SCOPE_AGENT);
                const unsigned tgt = (unsigned)(t+1);
                unsigned* fp = flagbase + (size_t)(bc*32 + (tid & 31))*16;
                unsigned spins = 0;
                bool done = false;
                while (!done && spins < (1u<<20)){
                    unsigned v = tgt;
                    if (tid < 32)
                        v = __hip_atomic_load(fp, __ATOMIC_RELAXED, __HIP_MEMORY_SCOPE_AGENT);
                    done = (bool)__all((int)(v >= tgt));
                    spins++;
                }
            }
        }
        __syncthreads();
    }

    if (tid < 128)
        cfin[(size_t)(bc*8 + ub)*HID + hid0 + uh] = creg;
}

__global__ __launch_bounds__(256, 2) void lstm_layer_k(
    const float* Xp, const float* Whh, const float* hinit, const float* cinit,
    float* ys, float* cfin, int T, unsigned* flagbase,
    unsigned short* phi, unsigned short* plo)
{
    lstm_body(Xp, Whh, hinit, cinit, ys, cfin, T, flagbase, blockIdx.x, phi, plo);
}

__global__ __launch_bounds__(256, 2) void lstm_dual_k(
    const float* Xp0, const float* Whh0, const float* hi0, const float* ci0,
    float* ys0, float* cf0, int T0, unsigned* fl0,
    unsigned short* phi0, unsigned short* plo0,
    const float* Xp1, const float* Whh1, const float* hi1, const float* ci1,
    float* ys1, float* cf1, int T1, unsigned* fl1,
    unsigned short* phi1, unsigned short* plo1)
{
    const int role = blockIdx.x >> 8;
    const int bx = blockIdx.x & 255;
    if (role == 0)
        lstm_body(Xp0, Whh0, hi0, ci0, ys0, cf0, T0, fl0, bx, phi0, plo0);
    else
        lstm_body(Xp1, Whh1, hi1, ci1, ys1, cf1, T1, fl1, bx, phi1, plo1);
}

extern "C" void kernel_launch(void* const* d_in, const int* in_sizes, int n_in,
                              void* d_out, int out_size, void* d_ws, size_t ws_size,
                              hipStream_t stream) {
    const int*   src      = (const int*)  d_in[0];
    const int*   trg      = (const int*)  d_in[1];
    const float* enc_emb  = (const float*)d_in[2];
    const float* enc_Wih0 = (const float*)d_in[3];
    const float* enc_Whh0 = (const float*)d_in[4];
    const float* enc_b0   = (const float*)d_in[5];
    const float* enc_Wih1 = (const float*)d_in[6];
    const float* enc_Whh1 = (const float*)d_in[7];
    const float* enc_b1   = (const float*)d_in[8];
    const float* dec_emb  = (const float*)d_in[9];
    const float* dec_Wih0 = (const float*)d_in[10];
    const float* dec_Whh0 = (const float*)d_in[11];
    const float* dec_b0   = (const float*)d_in[12];
    const float* dec_Wih1 = (const float*)d_in[13];
    const float* dec_Whh1 = (const float*)d_in[14];
    const float* dec_b1   = (const float*)d_in[15];
    const float* out_W    = (const float*)d_in[16];
    const float* out_b    = (const float*)d_in[17];

    // Big transient scratch in d_out (fp32, 100.35M elems); all dead before final GEMM.
    float* ob = (float*)d_out;
    float* Xp   = ob;                         // [3200,2048]
    float* xe   = ob + (size_t)6553600;       // fp32 fallback only
    float* xd   = ob + (size_t)7372800;       // fp32 fallback only
    float* eys0 = ob + (size_t)8175616;       // [50*64,512]
    float* eys1 = ob + (size_t)9814016;       // [50*64,512]
    float* dys0 = ob + (size_t)11452416;      // [49*64,512]
    float* Xp2  = ob + (size_t)13058048;      // [3136,2048]

    // d_ws layout (identical to rounds 13-15).
    float* ws = (float*)d_ws;
    float* dys1 = ws;                              // [49*64,512]
    float* c0   = ws + (size_t)1605632;
    float* c1   = ws + (size_t)1638400;
    float* hz   = ws + (size_t)1671168;
    unsigned* flags = (unsigned*)(ws + (size_t)1703936); // 16384 uints
    unsigned short* Whi = (unsigned short*)(ws + (size_t)1720320);
    unsigned short* Wlo = Whi + (size_t)16384000;  // unused (1-pass final)
    unsigned short* Ahi = Wlo + (size_t)16384000;
    unsigned short* Alo = Ahi + (size_t)1638400;   // 3200*512 (padded rows)
    unsigned short* eW0h = Alo  + (size_t)1638400;
    unsigned short* eW0l = eW0h + (size_t)524288;
    unsigned short* eW1h = eW0l + (size_t)524288;
    unsigned short* eW1l = eW1h + (size_t)1048576;
    unsigned short* dW0h = eW1l + (size_t)1048576;
    unsigned short* dW0l = dW0h + (size_t)524288;
    unsigned short* dW1h = dW0l + (size_t)524288;
    unsigned short* dW1l = dW1h + (size_t)1048576;
    unsigned short* XAh  = dW1l + (size_t)1048576;
    unsigned short* XAl  = XAh  + (size_t)1638400;
    const size_t end_final = (size_t)1720320*4 + ((size_t)16384000 + 1638400)*2*2;
    const size_t end_xp    = end_final + ((size_t)6291456 + 3276800)*2;
    const bool xp_ok = (ws_size >= end_xp);

    // zero c0,c1,hz + flags
    {
        int n = 3*BATCH*HID + 4*4096;
        zero_kernel<<<(n+255)/256, 256, 0, stream>>>(c0, n);
    }

    if (xp_ok){
        split_hi_kernel<<<(16384000/4 + 255)/256, 256, 0, stream>>>(out_W, Whi, 16384000/4);
        split_kernel<<<(524288/4 + 255)/256, 256, 0, stream>>>(enc_Wih0, eW0h, eW0l, 524288/4);
        split_kernel<<<(1048576/4 + 255)/256, 256, 0, stream>>>(enc_Wih1, eW1h, eW1l, 1048576/4);
        split_kernel<<<(524288/4 + 255)/256, 256, 0, stream>>>(dec_Wih0, dW0h, dW0l, 524288/4);
        split_kernel<<<(1048576/4 + 255)/256, 256, 0, stream>>>(dec_Wih1, dW1h, dW1l, 1048576/4);
        // embeddings straight into planes: src -> XAh/XAl (encL0 A), trg -> Ahi/Alo (decL0 A)
        embed_plane_kernel<<<(50*BATCH*(EMB/4)+255)/256, 256, 0, stream>>>(src, enc_emb, XAh, XAl, 50);
        embed_plane_kernel<<<(49*BATCH*(EMB/4)+255)/256, 256, 0, stream>>>(trg, dec_emb, Ahi, Alo, 49);
    } else {
        embed_kernel<<<(50*BATCH*(EMB/4)+255)/256, 256, 0, stream>>>(src, enc_emb, xe, 50);
        embed_kernel<<<(49*BATCH*(EMB/4)+255)/256, 256, 0, stream>>>(trg, dec_emb, xd, 49);
    }

    dim3 xgrid(G4/128, 25);   // fallback grid

    // ---- encoder layer 0 ----
    if (xp_ok)
        gemm_planes_gll<EMB, G4, 16, 3><<<400, 256, 0, stream>>>(XAh, XAl, eW0h, eW0l, enc_b0, Xp, 3200);
    else
        gemm_mfma_split<EMB, G4><<<xgrid, 256, 0, stream>>>(xe, enc_Wih0, enc_b0, Xp, 3200);
    // encL0 lstm emits eys0 planes -> XAh/XAl (consumed by encL1 Xp GEMM)
    lstm_layer_k<<<256, 256, 0, stream>>>(Xp, enc_Whh0, hz, hz, eys0, c0, 50, flags + 0,
                                          xp_ok ? XAh : nullptr, XAl);

    // ---- Xp for encoder layer 1 and decoder layer 0 ----
    if (xp_ok){
        gemm_planes_gll<HID, G4, 16, 3><<<400, 256, 0, stream>>>(XAh, XAl, eW1h, eW1l, enc_b1, Xp, 3200);
        gemm_planes_gll<EMB, G4, 16, 3><<<400, 256, 0, stream>>>(Ahi, Alo, dW0h, dW0l, dec_b0, Xp2, 3136);
    } else {
        gemm_mfma_split<HID, G4><<<xgrid, 256, 0, stream>>>(eys0, enc_Wih1, enc_b1, Xp, 3200);
        gemm_mfma_split<EMB, G4><<<xgrid, 256, 0, stream>>>(xd, dec_Wih0, dec_b0, Xp2, 3136);
    }

    // ---- encoder layer 1 AND decoder layer 0 concurrently ----
    // decL0 emits dys0 planes -> XAh/XAl (consumed by decL1 Xp GEMM); encL1 emits none.
    lstm_dual_k<<<512, 256, 0, stream>>>(
        Xp,  enc_Whh1, hz,                          hz, eys1, c1, 50, flags + 4096,  nullptr, nullptr,
        Xp2, dec_Whh0, eys0 + (size_t)49*BATCH*HID, c0, dys0, c0, 49, flags + 8192,
        xp_ok ? XAh : nullptr, XAl);

    // ---- decoder layer 1 ----
    if (xp_ok)
        gemm_planes_gll<HID, G4, 16, 3><<<400, 256, 0, stream>>>(XAh, XAl, dW1h, dW1l, dec_b1, Xp, 3136);
    else
        gemm_mfma_split<HID, G4><<<xgrid, 256, 0, stream>>>(dys0, dec_Wih1, dec_b1, Xp, 3136);
    // decL1 lstm emits dys1 planes -> Ahi/Alo (consumed by final GEMM, hi only)
    lstm_layer_k<<<256, 256, 0, stream>>>(Xp, dec_Whh1, eys1 + (size_t)49*BATCH*HID, c1,
                                          dys1, c1, 49, flags + 12288,
                                          xp_ok ? Ahi : nullptr, Alo);

    // ---- final projection -> fp32 d_out [3136, 32000]: 1-pass bf16, n-fastest ----
    if (xp_ok){
        gemm_planes_gll<HID, VOCAB, 250, 1><<<6250, 256, 0, stream>>>(
            Ahi, Ahi, Whi, Whi, out_b, (float*)d_out, 3136);
    } else {
        gemm_mfma_split<HID, VOCAB><<<dim3(VOCAB/128, 25), 256, 0, stream>>>(
            dys1, out_W, out_b, (float*)d_out, 3136);
    }
}